// Round 19
// baseline (329.055 us; speedup 1.0000x reference)
//
#include <hip/hip_runtime.h>

#define NUM_USERS 100000
#define NUM_ITEMS 50000
#define NNZ       2400000
#define EMB       64
#define NTOT      (NUM_USERS + NUM_ITEMS)
#define NQ        16384
#define NBKT      ((NTOT + 255) / 256)        // 586 buckets of 256 rows
#define NAB       ((NNZ + 8191) / 8192)       // append blocks = 293 (8 edges/thread)
#define BCAP      4608                        // bucket capacity (mean 4096 + 8 sigma)
#define BCAP_LO   4096
#define SPILLCAP  32768

typedef unsigned short ushort_t;
typedef unsigned int   uint_t;

// ---------- bf16 helpers (RNE pack, exact unpack) ----------
__device__ __forceinline__ ushort_t f2bf(float f) {
    uint_t u = __float_as_uint(f);
    u += 0x7FFFu + ((u >> 16) & 1u);          // round to nearest even
    return (ushort_t)(u >> 16);
}
__device__ __forceinline__ float bf2f_lo(uint_t w) {   // low 16 bits
    return __uint_as_float(w << 16);
}
__device__ __forceinline__ float bf2f_hi(uint_t w) {   // high 16 bits
    return __uint_as_float(w & 0xFFFF0000u);
}

// ---------- nt helper (scalar element type only) ----------
__device__ __forceinline__ int2 nt_load_i2(const int2* p) {
    unsigned long long u = __builtin_nontemporal_load((const unsigned long long*)p);
    int2 r; r.x = (int)(u & 0xFFFFFFFFull); r.y = (int)(u >> 32);
    return r;
}

// ---------- prologue: fp32 (eu|ei) -> bf16 concat cur0 ----------
__global__ void cvt_kernel(const float* __restrict__ eu,
                           const float* __restrict__ ei,
                           ushort_t* __restrict__ cur) {
    int idx = blockIdx.x * blockDim.x + threadIdx.x;   // one float4 -> 4 bf16
    const int total4 = NTOT * EMB / 4;
    const int user4  = NUM_USERS * EMB / 4;
    if (idx >= total4) return;
    float4 v = (idx < user4) ? ((const float4*)eu)[idx]
                             : ((const float4*)ei)[idx - user4];
    uint2 o;
    o.x = (uint_t)f2bf(v.x) | ((uint_t)f2bf(v.y) << 16);
    o.y = (uint_t)f2bf(v.z) | ((uint_t)f2bf(v.w) << 16);
    ((uint2*)cur)[idx] = o;
}

// layer-0 query init (fp32 path, exact)
__global__ void gather_init_kernel(const int* __restrict__ users,
                                   const int* __restrict__ items,
                                   const float* __restrict__ eu,
                                   const float* __restrict__ ei,
                                   float* __restrict__ uacc,
                                   float* __restrict__ iacc) {
    int idx = blockIdx.x * blockDim.x + threadIdx.x;
    if (idx >= NQ * 16) return;
    int j = idx >> 4;
    int t = idx & 15;
    ((float4*)uacc)[idx] = ((const float4*)eu)[(size_t)users[j] * 16 + t];
    ((float4*)iacc)[idx] = ((const float4*)ei)[(size_t)items[j] * 16 + t];
}

__global__ void dot_kernel(const float* __restrict__ uacc,
                           const float* __restrict__ iacc,
                           float* __restrict__ out) {
    int idx = blockIdx.x * blockDim.x + threadIdx.x;
    int j = idx >> 6;
    if (j >= NQ) return;
    int d = idx & 63;
    float p = uacc[(size_t)j * EMB + d] * iacc[(size_t)j * EMB + d];
    #pragma unroll
    for (int o = 32; o > 0; o >>= 1) p += __shfl_down(p, o);
    if (d == 0) out[j] = p * (1.0f / 16.0f);
}

// ---------- inverted query index: qhead[r] -> chain of slots ----------
__global__ void qbuild_kernel(const int* __restrict__ users,
                              const int* __restrict__ items,
                              int* __restrict__ qhead,
                              int* __restrict__ qnext) {
    int si = blockIdx.x * blockDim.x + threadIdx.x;
    if (si >= 2 * NQ) return;
    int r = (si < NQ) ? users[si] : (NUM_USERS + items[si - NQ]);
    qnext[si] = atomicExch(&qhead[r], si);
}

// ---------- build: LDS-aggregated fixed-capacity bucket append ----------

__global__ __launch_bounds__(1024) void append_agg_kernel(
        const int* __restrict__ row,
        const int* __restrict__ col,
        const float* __restrict__ val,
        int* __restrict__ ctr,
        int2* __restrict__ staging,
        int4* __restrict__ spill,
        int* __restrict__ spillcnt,
        int bcap) {
    __shared__ int cnt[NBKT];
    __shared__ int base[NBKT];
    int tid = threadIdx.x;
    if (tid < NBKT) cnt[tid] = 0;
    __syncthreads();

    int  myb[8], myr[8];
    int2 rec[8];
    int  rr[8], cc[8];
    int e0 = (blockIdx.x * 1024 + tid) * 8;
    bool any = (e0 < NNZ);                       // NNZ % 8 == 0 -> all-or-none
    if (any) {
        int4   r4a = *(const int4*)&row[e0];
        int4   r4b = *(const int4*)&row[e0 + 4];
        int4   c4a = *(const int4*)&col[e0];
        int4   c4b = *(const int4*)&col[e0 + 4];
        float4 v4a = *(const float4*)&val[e0];
        float4 v4b = *(const float4*)&val[e0 + 4];
        int   rs_[8] = {r4a.x, r4a.y, r4a.z, r4a.w, r4b.x, r4b.y, r4b.z, r4b.w};
        int   cs_[8] = {c4a.x, c4a.y, c4a.z, c4a.w, c4b.x, c4b.y, c4b.z, c4b.w};
        float vs_[8] = {v4a.x, v4a.y, v4a.z, v4a.w, v4b.x, v4b.y, v4b.z, v4b.w};
        #pragma unroll
        for (int j = 0; j < 8; ++j) {
            int r = rs_[j];
            int b = ((unsigned)r) >> 8;
            myb[j] = b;
            rr[j] = r; cc[j] = cs_[j];
            rec[j] = make_int2(((r & 255) << 18) | cs_[j], __float_as_int(vs_[j]));
            myr[j] = atomicAdd(&cnt[b], 1);      // local rank
        }
    }
    __syncthreads();
    if (tid < NBKT) {
        int c = cnt[tid];
        base[tid] = c ? atomicAdd(&ctr[tid], c) : 0;
    }
    __syncthreads();
    if (any) {
        #pragma unroll
        for (int j = 0; j < 8; ++j) {
            int p = base[myb[j]] + myr[j];
            if (p < bcap) {
                staging[(size_t)myb[j] * bcap + p] = rec[j];
            } else {
                int sp = atomicAdd(spillcnt, 1);
                if (sp < SPILLCAP) spill[sp] = make_int4(rr[j], cc[j], rec[j].y, 0);
            }
        }
    }
}

// ---------- within-bucket sort -> CSR (in place) + degree-sorted perm ----------

__global__ __launch_bounds__(512) void csr_fixed_kernel(
        const int* __restrict__ ctr,
        int2* __restrict__ staging,
        int* __restrict__ rs,                    // NBKT * 257
        int* __restrict__ perm,                  // NBKT * 256 (degree-ascending)
        int bcap) {
    __shared__ int2 recs[BCAP];
    __shared__ int cnt[256];
    __shared__ int sc[256];
    __shared__ int pos[256];
    __shared__ int dstart[64];
    int tid = threadIdx.x;
    int b = blockIdx.x;
    int base0 = b * bcap;
    int n = min(ctr[b], bcap);

    if (tid < 256) cnt[tid] = 0;
    if (tid >= 256 && tid < 320) dstart[tid - 256] = 0;   // reuse as histogram
    __syncthreads();
    for (int k = tid; k < n; k += 512) {
        int2 rec = nt_load_i2(&staging[base0 + k]);
        recs[k] = rec;
        atomicAdd(&cnt[((unsigned)rec.x) >> 18], 1);
    }
    __syncthreads();
    if (tid < 256) sc[tid] = cnt[tid];
    __syncthreads();
    #pragma unroll
    for (int o = 1; o < 256; o <<= 1) {          // Hillis-Steele inclusive scan
        int v = 0;
        if (tid < 256 && tid >= o) v = sc[tid - o];
        __syncthreads();
        if (tid < 256) sc[tid] += v;
        __syncthreads();
    }
    if (tid < 256) {
        int p = sc[tid] - cnt[tid];              // exclusive
        pos[tid] = p;
        rs[b * 257 + tid] = base0 + p;           // unconditional (phantoms: p == n)
        atomicAdd(&dstart[min(cnt[tid], 63)], 1); // degree histogram (dstart=counts)
    }
    if (tid == 0) rs[b * 257 + 256] = base0 + n;
    __syncthreads();
    if (tid == 0) {                               // tiny 64-bin exclusive scan
        int run = 0;
        #pragma unroll
        for (int i = 0; i < 64; ++i) { int c = dstart[i]; dstart[i] = run; run += c; }
    }
    __syncthreads();
    if (tid < 256) {                              // counting-sort rows by degree
        int d = min(cnt[tid], 63);
        int p = atomicAdd(&dstart[d], 1);
        perm[b * 256 + p] = tid;
    }
    for (int k = tid; k < n; k += 512) {
        int2 rec = recs[k];
        int rl = ((unsigned)rec.x) >> 18;
        int p = atomicAdd(&pos[rl], 1);
        staging[base0 + p] = make_int2(rec.x & 0x3FFFF, rec.y);
    }
}

// ---------- SpMM (bf16, group-per-row): 8-lane group per row, 8 rows/wave;
// lane t owns dims 8t..8t+7 -> NO cross-lane reduce. 4-edge unroll: 4
// group-uniform record loads + 4 gathers (8x128B lines each). Waves take
// degree-sorted rows (perm) so the 8 groups finish together. ----------

__global__ __launch_bounds__(256) void spmm_csr_kernel(
        const int* __restrict__ rs,
        const int* __restrict__ perm,
        const int2* __restrict__ pairs,
        const ushort_t* __restrict__ cur,        // bf16 [NTOT][EMB]
        ushort_t* __restrict__ next,             // bf16 [NTOT][EMB]
        const int* __restrict__ qhead,
        const int* __restrict__ qnext,
        float* __restrict__ uacc) {              // fp32, uacc|iacc contiguous
    int wave = (blockIdx.x * blockDim.x + threadIdx.x) >> 6;  // 32 waves/bucket
    int b = wave >> 5;
    if (b >= NBKT) return;
    int lw = wave & 31;
    int lane = threadIdx.x & 63;
    int g = lane >> 3;         // group 0..7 (one row each)
    int t = lane & 7;          // dim octant 0..7 (dims 8t..8t+7)
    int rl = perm[b * 256 + lw * 8 + g];         // degree-sorted local row
    int r = b * 256 + rl;
    int s = rs[b * 257 + rl];
    int e = rs[b * 257 + rl + 1];
    float a0 = 0.f, a1 = 0.f, a2 = 0.f, a3 = 0.f;
    float a4 = 0.f, a5 = 0.f, a6 = 0.f, a7 = 0.f;
    for (int i0 = s; i0 < e; i0 += 4) {
        int   c[4];
        float v[4];
        #pragma unroll
        for (int k = 0; k < 4; ++k) {
            int idx = i0 + k;
            bool ok = idx < e;
            int2 cv = nt_load_i2(&pairs[ok ? idx : s]);  // group-uniform addr
            c[k] = cv.x;
            v[k] = ok ? __int_as_float(cv.y) : 0.f;
        }
        #pragma unroll
        for (int k = 0; k < 4; ++k) {
            uint4 q4 = ((const uint4*)(cur + (size_t)c[k] * EMB))[t]; // 16B = 8 bf16
            a0 += v[k] * bf2f_lo(q4.x); a1 += v[k] * bf2f_hi(q4.x);
            a2 += v[k] * bf2f_lo(q4.y); a3 += v[k] * bf2f_hi(q4.y);
            a4 += v[k] * bf2f_lo(q4.z); a5 += v[k] * bf2f_hi(q4.z);
            a6 += v[k] * bf2f_lo(q4.w); a7 += v[k] * bf2f_hi(q4.w);
        }
    }
    if (r < NTOT) {
        uint4 o;
        o.x = (uint_t)f2bf(a0) | ((uint_t)f2bf(a1) << 16);
        o.y = (uint_t)f2bf(a2) | ((uint_t)f2bf(a3) << 16);
        o.z = (uint_t)f2bf(a4) | ((uint_t)f2bf(a5) << 16);
        o.w = (uint_t)f2bf(a6) | ((uint_t)f2bf(a7) << 16);
        ((uint4*)(next + (size_t)r * EMB))[t] = o;
        // fused per-layer query accumulate (fp32): lane t covers dims 8t..8t+7
        int si = qhead[r];                       // group-uniform
        while (si >= 0) {
            float4* dst = (float4*)&uacc[(size_t)si * EMB];
            float4 d0 = dst[2 * t], d1 = dst[2 * t + 1];
            d0.x += a0; d0.y += a1; d0.z += a2; d0.w += a3;
            d1.x += a4; d1.y += a5; d1.z += a6; d1.w += a7;
            dst[2 * t] = d0; dst[2 * t + 1] = d1;
            si = qnext[si];
        }
    }
}

// spill edges (statically ~unreachable at BCAP=mean+8sigma): CAS on bf16 pair
__global__ void spill_apply_kernel(const int4* __restrict__ spill,
                                   const int* __restrict__ spillcnt,
                                   const ushort_t* __restrict__ cur,
                                   ushort_t* __restrict__ next) {
    int n = min(*spillcnt, SPILLCAP);
    for (int idx = blockIdx.x * blockDim.x + threadIdx.x;
         idx < n * 32; idx += gridDim.x * blockDim.x) {
        int e = idx >> 5, w = idx & 31;          // word w covers dims 2w, 2w+1
        int4 rec = spill[e];
        float v = __int_as_float(rec.z);
        float g0 = bf2f_lo((uint_t)cur[(size_t)rec.y * EMB + 2 * w]);
        float g1 = bf2f_lo((uint_t)cur[(size_t)rec.y * EMB + 2 * w + 1]);
        uint_t* addr = (uint_t*)(next + (size_t)rec.x * EMB + 2 * w);
        uint_t old = *addr, assumed;
        do {
            assumed = old;
            float o0 = bf2f_lo(assumed);
            float o1 = bf2f_hi(assumed);
            uint_t nw = (uint_t)f2bf(o0 + v * g0) | ((uint_t)f2bf(o1 + v * g1) << 16);
            old = atomicCAS(addr, assumed, nw);
        } while (old != assumed);
    }
}

// ---------- fallback path (ws too small): fp32 atomic SpMM ----------

__global__ void init_cur_kernel(const float* __restrict__ eu,
                                const float* __restrict__ ei,
                                float* __restrict__ cur) {
    int idx = blockIdx.x * blockDim.x + threadIdx.x;
    const int total4 = NTOT * EMB / 4;
    const int user4  = NUM_USERS * EMB / 4;
    if (idx < total4) {
        float4 v;
        if (idx < user4) v = ((const float4*)eu)[idx];
        else             v = ((const float4*)ei)[idx - user4];
        ((float4*)cur)[idx] = v;
    }
}

__global__ void gather_add_kernel(const int* __restrict__ users,
                                  const int* __restrict__ items,
                                  const float* __restrict__ src,
                                  float* __restrict__ uacc,
                                  float* __restrict__ iacc) {
    int idx = blockIdx.x * blockDim.x + threadIdx.x;
    if (idx >= NQ * 16) return;
    int j = idx >> 4;
    int t = idx & 15;
    float4 uv = ((const float4*)src)[(size_t)users[j] * 16 + t];
    float4 iv = ((const float4*)src)[(size_t)(NUM_USERS + items[j]) * 16 + t];
    float4* up = (float4*)uacc + idx;
    float4* ip = (float4*)iacc + idx;
    float4 a = *up, b = *ip;
    a.x += uv.x; a.y += uv.y; a.z += uv.z; a.w += uv.w;
    b.x += iv.x; b.y += iv.y; b.z += iv.z; b.w += iv.w;
    *up = a; *ip = b;
}

__global__ void spmm_atomic_kernel(const int* __restrict__ row,
                                   const int* __restrict__ col,
                                   const float* __restrict__ val,
                                   const float* __restrict__ cur,
                                   float* __restrict__ next) {
    long long idx = (long long)blockIdx.x * blockDim.x + threadIdx.x;
    if (idx >= (long long)NNZ * EMB) return;
    int e = (int)(idx >> 6);
    int d = (int)(idx & 63);
    atomicAdd(&next[row[e] * EMB + d], val[e] * cur[col[e] * EMB + d]);
}

extern "C" void kernel_launch(void* const* d_in, const int* in_sizes, int n_in,
                              void* d_out, int out_size, void* d_ws, size_t ws_size,
                              hipStream_t stream) {
    const int*   row   = (const int*)d_in[0];
    const int*   col   = (const int*)d_in[1];
    const float* val   = (const float*)d_in[2];
    const float* eu    = (const float*)d_in[3];
    const float* ei    = (const float*)d_in[4];
    const int*   users = (const int*)d_in[5];
    const int*   items = (const int*)d_in[6];
    float*       out   = (float*)d_out;

    // primary workspace layout (bf16 layer buffers)
    ushort_t* bufA = (ushort_t*)d_ws;                    // NTOT*EMB bf16
    ushort_t* bufB = bufA + (size_t)NTOT * EMB;          // NTOT*EMB bf16
    float* uacc = (float*)(bufB + (size_t)NTOT * EMB);   // NQ*EMB f32
    float* iacc = uacc + (size_t)NQ * EMB;               // NQ*EMB f32 (contiguous!)
    int*   ctr  = (int*)(iacc + (size_t)NQ * EMB);       // NBKT
    int*   rs   = ctr + NBKT;                            // NBKT*257
    int*   spillcnt = rs + NBKT * 257;                   // 4
    int*   qhead = spillcnt + 4;                         // NTOT
    int*   qnext = qhead + NTOT;                         // 2*NQ
    int*   perm = qnext + 2 * NQ;                        // NBKT*256
    int4*  spill = (int4*)(perm + NBKT * 256);           // SPILLCAP
    int2*  staging = (int2*)(spill + SPILLCAP);          // NBKT*bcap

    size_t fixed_bytes = (size_t)((char*)staging - (char*)d_ws);
    size_t needHi = fixed_bytes + (size_t)NBKT * BCAP * sizeof(int2);
    size_t needLo = fixed_bytes + (size_t)NBKT * BCAP_LO * sizeof(int2);
    int bcap = (ws_size >= needHi) ? BCAP : ((ws_size >= needLo) ? BCAP_LO : 0);

    if (bcap > 0) {
        gather_init_kernel<<<(NQ * 16 + 255) / 256, 256, 0, stream>>>(users, items, eu, ei, uacc, iacc);
        cvt_kernel<<<(NTOT * 16 + 255) / 256, 256, 0, stream>>>(eu, ei, bufA);
        (void)hipMemsetAsync(ctr, 0, NBKT * sizeof(int), stream);
        (void)hipMemsetAsync(spillcnt, 0, 4 * sizeof(int), stream);
        (void)hipMemsetAsync(qhead, 0xFF, NTOT * sizeof(int), stream);
        qbuild_kernel<<<(2 * NQ + 255) / 256, 256, 0, stream>>>(users, items, qhead, qnext);
        append_agg_kernel<<<NAB, 1024, 0, stream>>>(row, col, val, ctr, staging,
                                                    spill, spillcnt, bcap);
        csr_fixed_kernel<<<NBKT, 512, 0, stream>>>(ctr, staging, rs, perm, bcap);

        ushort_t* cur = bufA;
        ushort_t* nxt = bufB;
        for (int l = 0; l < 3; ++l) {
            spmm_csr_kernel<<<NBKT * 8, 256, 0, stream>>>(
                rs, perm, staging, cur, nxt, qhead, qnext, uacc);
            spill_apply_kernel<<<64, 256, 0, stream>>>(spill, spillcnt, cur, nxt);
            ushort_t* tmp = cur; cur = nxt; nxt = tmp;
        }
    } else {
        // fallback (fp32): own layout — bufA32, bufB32, uacc, iacc
        float* bufA32 = (float*)d_ws;
        float* bufB32 = bufA32 + (size_t)NTOT * EMB;
        float* uacc32 = bufB32 + (size_t)NTOT * EMB;
        float* iacc32 = uacc32 + (size_t)NQ * EMB;
        gather_init_kernel<<<(NQ * 16 + 255) / 256, 256, 0, stream>>>(users, items, eu, ei, uacc32, iacc32);
        init_cur_kernel<<<(NTOT * EMB / 4 + 255) / 256, 256, 0, stream>>>(eu, ei, bufA32);
        float* cur = bufA32;
        float* nxt = bufB32;
        const long long spmm_threads = (long long)NNZ * EMB;
        for (int l = 0; l < 3; ++l) {
            (void)hipMemsetAsync(nxt, 0, (size_t)NTOT * EMB * sizeof(float), stream);
            spmm_atomic_kernel<<<(int)((spmm_threads + 255) / 256), 256, 0, stream>>>(row, col, val, cur, nxt);
            gather_add_kernel<<<(NQ * 16 + 255) / 256, 256, 0, stream>>>(users, items, nxt, uacc32, iacc32);
            float* t = cur; cur = nxt; nxt = t;
        }
        dot_kernel<<<(NQ * EMB + 255) / 256, 256, 0, stream>>>(uacc32, iacc32, out);
        return;
    }

    dot_kernel<<<(NQ * EMB + 255) / 256, 256, 0, stream>>>(uacc, iacc, out);
}

// Round 20
// 269.788 us; speedup vs baseline: 1.2197x; 1.2197x over previous
//
#include <hip/hip_runtime.h>

#define NUM_USERS 100000
#define NUM_ITEMS 50000
#define NNZ       2400000
#define EMB       64
#define NTOT      (NUM_USERS + NUM_ITEMS)
#define NQ        16384
#define NBKT      ((NTOT + 255) / 256)        // 586 buckets of 256 rows
#define NAB       ((NNZ + 8191) / 8192)       // append blocks = 293 (8 edges/thread)
#define BCAP      4608                        // bucket capacity (mean 4096 + 8 sigma)
#define BCAP_LO   4096
#define SPILLCAP  32768

typedef unsigned short ushort_t;
typedef unsigned int   uint_t;

// ---------- bf16 helpers (RNE pack, exact unpack) ----------
__device__ __forceinline__ ushort_t f2bf(float f) {
    uint_t u = __float_as_uint(f);
    u += 0x7FFFu + ((u >> 16) & 1u);          // round to nearest even
    return (ushort_t)(u >> 16);
}
__device__ __forceinline__ float bf2f_lo(uint_t w) {   // low 16 bits
    return __uint_as_float(w << 16);
}
__device__ __forceinline__ float bf2f_hi(uint_t w) {   // high 16 bits
    return __uint_as_float(w & 0xFFFF0000u);
}

// ---------- nt helper (scalar element type only) ----------
__device__ __forceinline__ int2 nt_load_i2(const int2* p) {
    unsigned long long u = __builtin_nontemporal_load((const unsigned long long*)p);
    int2 r; r.x = (int)(u & 0xFFFFFFFFull); r.y = (int)(u >> 32);
    return r;
}

// ---------- prologue: fp32 (eu|ei) -> bf16 concat cur0 ----------
__global__ void cvt_kernel(const float* __restrict__ eu,
                           const float* __restrict__ ei,
                           ushort_t* __restrict__ cur) {
    int idx = blockIdx.x * blockDim.x + threadIdx.x;   // one float4 -> 4 bf16
    const int total4 = NTOT * EMB / 4;
    const int user4  = NUM_USERS * EMB / 4;
    if (idx >= total4) return;
    float4 v = (idx < user4) ? ((const float4*)eu)[idx]
                             : ((const float4*)ei)[idx - user4];
    uint2 o;
    o.x = (uint_t)f2bf(v.x) | ((uint_t)f2bf(v.y) << 16);
    o.y = (uint_t)f2bf(v.z) | ((uint_t)f2bf(v.w) << 16);
    ((uint2*)cur)[idx] = o;
}

// layer-0 query init (fp32 path, exact)
__global__ void gather_init_kernel(const int* __restrict__ users,
                                   const int* __restrict__ items,
                                   const float* __restrict__ eu,
                                   const float* __restrict__ ei,
                                   float* __restrict__ uacc,
                                   float* __restrict__ iacc) {
    int idx = blockIdx.x * blockDim.x + threadIdx.x;
    if (idx >= NQ * 16) return;
    int j = idx >> 4;
    int t = idx & 15;
    ((float4*)uacc)[idx] = ((const float4*)eu)[(size_t)users[j] * 16 + t];
    ((float4*)iacc)[idx] = ((const float4*)ei)[(size_t)items[j] * 16 + t];
}

__global__ void dot_kernel(const float* __restrict__ uacc,
                           const float* __restrict__ iacc,
                           float* __restrict__ out) {
    int idx = blockIdx.x * blockDim.x + threadIdx.x;
    int j = idx >> 6;
    if (j >= NQ) return;
    int d = idx & 63;
    float p = uacc[(size_t)j * EMB + d] * iacc[(size_t)j * EMB + d];
    #pragma unroll
    for (int o = 32; o > 0; o >>= 1) p += __shfl_down(p, o);
    if (d == 0) out[j] = p * (1.0f / 16.0f);
}

// ---------- inverted query index: qhead[r] -> chain of slots ----------
__global__ void qbuild_kernel(const int* __restrict__ users,
                              const int* __restrict__ items,
                              int* __restrict__ qhead,
                              int* __restrict__ qnext) {
    int si = blockIdx.x * blockDim.x + threadIdx.x;
    if (si >= 2 * NQ) return;
    int r = (si < NQ) ? users[si] : (NUM_USERS + items[si - NQ]);
    qnext[si] = atomicExch(&qhead[r], si);
}

// compact list of rows with a non-empty query chain (for the last layer)
__global__ void qlist_kernel(const int* __restrict__ qhead,
                             int* __restrict__ qrows,
                             int* __restrict__ qcnt) {
    int r = blockIdx.x * blockDim.x + threadIdx.x;
    if (r >= NTOT) return;
    if (qhead[r] >= 0) {
        int p = atomicAdd(qcnt, 1);
        qrows[p] = r;
    }
}

// ---------- build: LDS-aggregated fixed-capacity bucket append ----------

__global__ __launch_bounds__(1024) void append_agg_kernel(
        const int* __restrict__ row,
        const int* __restrict__ col,
        const float* __restrict__ val,
        int* __restrict__ ctr,
        int2* __restrict__ staging,
        int4* __restrict__ spill,
        int* __restrict__ spillcnt,
        int bcap) {
    __shared__ int cnt[NBKT];
    __shared__ int base[NBKT];
    int tid = threadIdx.x;
    if (tid < NBKT) cnt[tid] = 0;
    __syncthreads();

    int  myb[8], myr[8];
    int2 rec[8];
    int  rr[8], cc[8];
    int e0 = (blockIdx.x * 1024 + tid) * 8;
    bool any = (e0 < NNZ);                       // NNZ % 8 == 0 -> all-or-none
    if (any) {
        int4   r4a = *(const int4*)&row[e0];
        int4   r4b = *(const int4*)&row[e0 + 4];
        int4   c4a = *(const int4*)&col[e0];
        int4   c4b = *(const int4*)&col[e0 + 4];
        float4 v4a = *(const float4*)&val[e0];
        float4 v4b = *(const float4*)&val[e0 + 4];
        int   rs_[8] = {r4a.x, r4a.y, r4a.z, r4a.w, r4b.x, r4b.y, r4b.z, r4b.w};
        int   cs_[8] = {c4a.x, c4a.y, c4a.z, c4a.w, c4b.x, c4b.y, c4b.z, c4b.w};
        float vs_[8] = {v4a.x, v4a.y, v4a.z, v4a.w, v4b.x, v4b.y, v4b.z, v4b.w};
        #pragma unroll
        for (int j = 0; j < 8; ++j) {
            int r = rs_[j];
            int b = ((unsigned)r) >> 8;
            myb[j] = b;
            rr[j] = r; cc[j] = cs_[j];
            rec[j] = make_int2(((r & 255) << 18) | cs_[j], __float_as_int(vs_[j]));
            myr[j] = atomicAdd(&cnt[b], 1);      // local rank
        }
    }
    __syncthreads();
    if (tid < NBKT) {
        int c = cnt[tid];
        base[tid] = c ? atomicAdd(&ctr[tid], c) : 0;
    }
    __syncthreads();
    if (any) {
        #pragma unroll
        for (int j = 0; j < 8; ++j) {
            int p = base[myb[j]] + myr[j];
            if (p < bcap) {
                staging[(size_t)myb[j] * bcap + p] = rec[j];
            } else {
                int sp = atomicAdd(spillcnt, 1);
                if (sp < SPILLCAP) spill[sp] = make_int4(rr[j], cc[j], rec[j].y, 0);
            }
        }
    }
}

// ---------- within-bucket sort -> CSR (in place, fixed segments) ----------

__global__ __launch_bounds__(512) void csr_fixed_kernel(
        const int* __restrict__ ctr,
        int2* __restrict__ staging,
        int* __restrict__ rs,                    // NBKT * 257
        int bcap) {
    __shared__ int2 recs[BCAP];
    __shared__ int cnt[256];
    __shared__ int sc[256];
    __shared__ int pos[256];
    int tid = threadIdx.x;
    int b = blockIdx.x;
    int base0 = b * bcap;
    int n = min(ctr[b], bcap);

    if (tid < 256) cnt[tid] = 0;
    __syncthreads();
    for (int k = tid; k < n; k += 512) {
        int2 rec = nt_load_i2(&staging[base0 + k]);
        recs[k] = rec;
        atomicAdd(&cnt[((unsigned)rec.x) >> 18], 1);
    }
    __syncthreads();
    if (tid < 256) sc[tid] = cnt[tid];
    __syncthreads();
    #pragma unroll
    for (int o = 1; o < 256; o <<= 1) {          // Hillis-Steele inclusive scan
        int v = 0;
        if (tid < 256 && tid >= o) v = sc[tid - o];
        __syncthreads();
        if (tid < 256) sc[tid] += v;
        __syncthreads();
    }
    if (tid < 256) {
        int p = sc[tid] - cnt[tid];              // exclusive
        pos[tid] = p;
        rs[b * 257 + tid] = base0 + p;           // unconditional (phantoms: p == n)
    }
    if (tid == 0) rs[b * 257 + 256] = base0 + n;
    __syncthreads();
    for (int k = tid; k < n; k += 512) {
        int2 rec = recs[k];
        int rl = ((unsigned)rec.x) >> 18;
        int p = atomicAdd(&pos[rl], 1);
        staging[base0 + p] = make_int2(rec.x & 0x3FFFF, rec.y);
    }
}

// ---------- SpMM (R18 form): one wave per row; lane = (edge-slot q 0..7, t 0..7);
// 16B gathers (one instr = 8 distinct rows); 16 edges/round; xor-reduce ----------

__global__ __launch_bounds__(256) void spmm_csr_kernel(
        const int* __restrict__ rs,
        const int2* __restrict__ pairs,
        const ushort_t* __restrict__ cur,        // bf16 [NTOT][EMB]
        ushort_t* __restrict__ next,             // bf16 [NTOT][EMB]
        const int* __restrict__ qhead,
        const int* __restrict__ qnext,
        float* __restrict__ uacc) {              // fp32, uacc|iacc contiguous
    int gid = blockIdx.x * blockDim.x + threadIdx.x;
    int r = gid >> 6;          // wave id = row
    if (r >= NTOT) return;
    int lane = threadIdx.x & 63;
    int q = lane >> 3;         // edge slot 0..7
    int t = lane & 7;          // dim octant 0..7 (dims 8t..8t+7)
    int b = r >> 8, i = r & 255;
    int s = rs[b * 257 + i];
    int e = rs[b * 257 + i + 1];
    float a0 = 0.f, a1 = 0.f, a2 = 0.f, a3 = 0.f;
    float a4 = 0.f, a5 = 0.f, a6 = 0.f, a7 = 0.f;
    for (int base = s; base < e; base += 16) {
        int   c[2];
        float v[2];
        #pragma unroll
        for (int k = 0; k < 2; ++k) {
            int idx = base + q + 8 * k;
            bool ok = idx < e;
            int2 cv = nt_load_i2(&pairs[ok ? idx : s]);  // 8 lanes share addr
            c[k] = cv.x;
            v[k] = ok ? __int_as_float(cv.y) : 0.f;
        }
        #pragma unroll
        for (int k = 0; k < 2; ++k) {
            uint4 g = ((const uint4*)(cur + (size_t)c[k] * EMB))[t];  // 16B = 8 bf16
            a0 += v[k] * bf2f_lo(g.x); a1 += v[k] * bf2f_hi(g.x);
            a2 += v[k] * bf2f_lo(g.y); a3 += v[k] * bf2f_hi(g.y);
            a4 += v[k] * bf2f_lo(g.z); a5 += v[k] * bf2f_hi(g.z);
            a6 += v[k] * bf2f_lo(g.w); a7 += v[k] * bf2f_hi(g.w);
        }
    }
    #pragma unroll
    for (int o = 8; o < 64; o <<= 1) {
        a0 += __shfl_xor(a0, o); a1 += __shfl_xor(a1, o);
        a2 += __shfl_xor(a2, o); a3 += __shfl_xor(a3, o);
        a4 += __shfl_xor(a4, o); a5 += __shfl_xor(a5, o);
        a6 += __shfl_xor(a6, o); a7 += __shfl_xor(a7, o);
    }
    if (q == 0) {
        uint4 o;
        o.x = (uint_t)f2bf(a0) | ((uint_t)f2bf(a1) << 16);
        o.y = (uint_t)f2bf(a2) | ((uint_t)f2bf(a3) << 16);
        o.z = (uint_t)f2bf(a4) | ((uint_t)f2bf(a5) << 16);
        o.w = (uint_t)f2bf(a6) | ((uint_t)f2bf(a7) << 16);
        ((uint4*)(next + (size_t)r * EMB))[t] = o;
        // fused per-layer query accumulate (fp32): lane t covers dims 8t..8t+7
        int si = qhead[r];                       // wave-uniform
        while (si >= 0) {
            float4* dst = (float4*)&uacc[(size_t)si * EMB];
            float4 d0 = dst[2 * t], d1 = dst[2 * t + 1];
            d0.x += a0; d0.y += a1; d0.z += a2; d0.w += a3;
            d1.x += a4; d1.y += a5; d1.z += a6; d1.w += a7;
            dst[2 * t] = d0; dst[2 * t + 1] = d1;
            si = qnext[si];
        }
    }
}

// ---------- last layer: only query rows (no next store, uacc accumulate only) ----

__global__ __launch_bounds__(256) void spmm_last_kernel(
        const int* __restrict__ rs,
        const int2* __restrict__ pairs,
        const ushort_t* __restrict__ cur,
        const int* __restrict__ qhead,
        const int* __restrict__ qnext,
        const int* __restrict__ qrows,
        const int* __restrict__ qcnt,
        float* __restrict__ uacc) {
    int wave = (blockIdx.x * blockDim.x + threadIdx.x) >> 6;
    if (wave >= *qcnt) return;
    int r = qrows[wave];
    int lane = threadIdx.x & 63;
    int q = lane >> 3;
    int t = lane & 7;
    int b = r >> 8, i = r & 255;
    int s = rs[b * 257 + i];
    int e = rs[b * 257 + i + 1];
    float a0 = 0.f, a1 = 0.f, a2 = 0.f, a3 = 0.f;
    float a4 = 0.f, a5 = 0.f, a6 = 0.f, a7 = 0.f;
    for (int base = s; base < e; base += 16) {
        int   c[2];
        float v[2];
        #pragma unroll
        for (int k = 0; k < 2; ++k) {
            int idx = base + q + 8 * k;
            bool ok = idx < e;
            int2 cv = nt_load_i2(&pairs[ok ? idx : s]);
            c[k] = cv.x;
            v[k] = ok ? __int_as_float(cv.y) : 0.f;
        }
        #pragma unroll
        for (int k = 0; k < 2; ++k) {
            uint4 g = ((const uint4*)(cur + (size_t)c[k] * EMB))[t];
            a0 += v[k] * bf2f_lo(g.x); a1 += v[k] * bf2f_hi(g.x);
            a2 += v[k] * bf2f_lo(g.y); a3 += v[k] * bf2f_hi(g.y);
            a4 += v[k] * bf2f_lo(g.z); a5 += v[k] * bf2f_hi(g.z);
            a6 += v[k] * bf2f_lo(g.w); a7 += v[k] * bf2f_hi(g.w);
        }
    }
    #pragma unroll
    for (int o = 8; o < 64; o <<= 1) {
        a0 += __shfl_xor(a0, o); a1 += __shfl_xor(a1, o);
        a2 += __shfl_xor(a2, o); a3 += __shfl_xor(a3, o);
        a4 += __shfl_xor(a4, o); a5 += __shfl_xor(a5, o);
        a6 += __shfl_xor(a6, o); a7 += __shfl_xor(a7, o);
    }
    if (q == 0) {
        int si = qhead[r];
        while (si >= 0) {
            float4* dst = (float4*)&uacc[(size_t)si * EMB];
            float4 d0 = dst[2 * t], d1 = dst[2 * t + 1];
            d0.x += a0; d0.y += a1; d0.z += a2; d0.w += a3;
            d1.x += a4; d1.y += a5; d1.z += a6; d1.w += a7;
            dst[2 * t] = d0; dst[2 * t + 1] = d1;
            si = qnext[si];
        }
    }
}

// spill edges (statically ~unreachable): CAS on bf16 pair of next
__global__ void spill_apply_kernel(const int4* __restrict__ spill,
                                   const int* __restrict__ spillcnt,
                                   const ushort_t* __restrict__ cur,
                                   ushort_t* __restrict__ next) {
    int n = min(*spillcnt, SPILLCAP);
    for (int idx = blockIdx.x * blockDim.x + threadIdx.x;
         idx < n * 32; idx += gridDim.x * blockDim.x) {
        int e = idx >> 5, w = idx & 31;          // word w covers dims 2w, 2w+1
        int4 rec = spill[e];
        float v = __int_as_float(rec.z);
        float g0 = bf2f_lo((uint_t)cur[(size_t)rec.y * EMB + 2 * w]);
        float g1 = bf2f_lo((uint_t)cur[(size_t)rec.y * EMB + 2 * w + 1]);
        uint_t* addr = (uint_t*)(next + (size_t)rec.x * EMB + 2 * w);
        uint_t old = *addr, assumed;
        do {
            assumed = old;
            float o0 = bf2f_lo(assumed);
            float o1 = bf2f_hi(assumed);
            uint_t nw = (uint_t)f2bf(o0 + v * g0) | ((uint_t)f2bf(o1 + v * g1) << 16);
            old = atomicCAS(addr, assumed, nw);
        } while (old != assumed);
    }
}

// last-layer spill (statically ~unreachable): add into uacc via query chain
__global__ void spill_apply_last_kernel(const int4* __restrict__ spill,
                                        const int* __restrict__ spillcnt,
                                        const ushort_t* __restrict__ cur,
                                        const int* __restrict__ qhead,
                                        const int* __restrict__ qnext,
                                        float* __restrict__ uacc) {
    int n = min(*spillcnt, SPILLCAP);
    for (int idx = blockIdx.x * blockDim.x + threadIdx.x;
         idx < n * EMB; idx += gridDim.x * blockDim.x) {
        int e = idx >> 6, d = idx & 63;
        int4 rec = spill[e];
        float v = __int_as_float(rec.z);
        float g = bf2f_lo((uint_t)cur[(size_t)rec.y * EMB + d]);
        int si = qhead[rec.x];
        while (si >= 0) {
            atomicAdd(&uacc[(size_t)si * EMB + d], v * g);
            si = qnext[si];
        }
    }
}

// ---------- fallback path (ws too small): fp32 atomic SpMM ----------

__global__ void init_cur_kernel(const float* __restrict__ eu,
                                const float* __restrict__ ei,
                                float* __restrict__ cur) {
    int idx = blockIdx.x * blockDim.x + threadIdx.x;
    const int total4 = NTOT * EMB / 4;
    const int user4  = NUM_USERS * EMB / 4;
    if (idx < total4) {
        float4 v;
        if (idx < user4) v = ((const float4*)eu)[idx];
        else             v = ((const float4*)ei)[idx - user4];
        ((float4*)cur)[idx] = v;
    }
}

__global__ void gather_add_kernel(const int* __restrict__ users,
                                  const int* __restrict__ items,
                                  const float* __restrict__ src,
                                  float* __restrict__ uacc,
                                  float* __restrict__ iacc) {
    int idx = blockIdx.x * blockDim.x + threadIdx.x;
    if (idx >= NQ * 16) return;
    int j = idx >> 4;
    int t = idx & 15;
    float4 uv = ((const float4*)src)[(size_t)users[j] * 16 + t];
    float4 iv = ((const float4*)src)[(size_t)(NUM_USERS + items[j]) * 16 + t];
    float4* up = (float4*)uacc + idx;
    float4* ip = (float4*)iacc + idx;
    float4 a = *up, b = *ip;
    a.x += uv.x; a.y += uv.y; a.z += uv.z; a.w += uv.w;
    b.x += iv.x; b.y += iv.y; b.z += iv.z; b.w += iv.w;
    *up = a; *ip = b;
}

__global__ void spmm_atomic_kernel(const int* __restrict__ row,
                                   const int* __restrict__ col,
                                   const float* __restrict__ val,
                                   const float* __restrict__ cur,
                                   float* __restrict__ next) {
    long long idx = (long long)blockIdx.x * blockDim.x + threadIdx.x;
    if (idx >= (long long)NNZ * EMB) return;
    int e = (int)(idx >> 6);
    int d = (int)(idx & 63);
    atomicAdd(&next[row[e] * EMB + d], val[e] * cur[col[e] * EMB + d]);
}

extern "C" void kernel_launch(void* const* d_in, const int* in_sizes, int n_in,
                              void* d_out, int out_size, void* d_ws, size_t ws_size,
                              hipStream_t stream) {
    const int*   row   = (const int*)d_in[0];
    const int*   col   = (const int*)d_in[1];
    const float* val   = (const float*)d_in[2];
    const float* eu    = (const float*)d_in[3];
    const float* ei    = (const float*)d_in[4];
    const int*   users = (const int*)d_in[5];
    const int*   items = (const int*)d_in[6];
    float*       out   = (float*)d_out;

    // primary workspace layout (bf16 layer buffers)
    ushort_t* bufA = (ushort_t*)d_ws;                    // NTOT*EMB bf16
    ushort_t* bufB = bufA + (size_t)NTOT * EMB;          // NTOT*EMB bf16
    float* uacc = (float*)(bufB + (size_t)NTOT * EMB);   // NQ*EMB f32
    float* iacc = uacc + (size_t)NQ * EMB;               // NQ*EMB f32 (contiguous!)
    int*   ctr  = (int*)(iacc + (size_t)NQ * EMB);       // NBKT
    int*   rs   = ctr + NBKT;                            // NBKT*257
    int*   spillcnt = rs + NBKT * 257;                   // 4
    int*   qcnt = spillcnt + 4;                          // 4
    int*   qhead = qcnt + 4;                             // NTOT
    int*   qnext = qhead + NTOT;                         // 2*NQ
    int*   qrows = qnext + 2 * NQ;                       // 2*NQ
    int4*  spill = (int4*)(qrows + 2 * NQ);              // SPILLCAP
    int2*  staging = (int2*)(spill + SPILLCAP);          // NBKT*bcap

    size_t fixed_bytes = (size_t)((char*)staging - (char*)d_ws);
    size_t needHi = fixed_bytes + (size_t)NBKT * BCAP * sizeof(int2);
    size_t needLo = fixed_bytes + (size_t)NBKT * BCAP_LO * sizeof(int2);
    int bcap = (ws_size >= needHi) ? BCAP : ((ws_size >= needLo) ? BCAP_LO : 0);

    if (bcap > 0) {
        gather_init_kernel<<<(NQ * 16 + 255) / 256, 256, 0, stream>>>(users, items, eu, ei, uacc, iacc);
        cvt_kernel<<<(NTOT * 16 + 255) / 256, 256, 0, stream>>>(eu, ei, bufA);
        (void)hipMemsetAsync(ctr, 0, NBKT * sizeof(int), stream);
        (void)hipMemsetAsync(spillcnt, 0, 8 * sizeof(int), stream);   // spillcnt + qcnt
        (void)hipMemsetAsync(qhead, 0xFF, NTOT * sizeof(int), stream);
        qbuild_kernel<<<(2 * NQ + 255) / 256, 256, 0, stream>>>(users, items, qhead, qnext);
        qlist_kernel<<<(NTOT + 255) / 256, 256, 0, stream>>>(qhead, qrows, qcnt);
        append_agg_kernel<<<NAB, 1024, 0, stream>>>(row, col, val, ctr, staging,
                                                    spill, spillcnt, bcap);
        csr_fixed_kernel<<<NBKT, 512, 0, stream>>>(ctr, staging, rs, bcap);

        ushort_t* cur = bufA;
        ushort_t* nxt = bufB;
        for (int l = 0; l < 2; ++l) {
            spmm_csr_kernel<<<(NTOT * 64 + 255) / 256, 256, 0, stream>>>(
                rs, staging, cur, nxt, qhead, qnext, uacc);
            spill_apply_kernel<<<64, 256, 0, stream>>>(spill, spillcnt, cur, nxt);
            ushort_t* tmp = cur; cur = nxt; nxt = tmp;
        }
        // last layer: only rows consumed by query chains; no next store
        spmm_last_kernel<<<(2 * NQ * 64 + 255) / 256, 256, 0, stream>>>(
            rs, staging, cur, qhead, qnext, qrows, qcnt, uacc);
        spill_apply_last_kernel<<<64, 256, 0, stream>>>(spill, spillcnt, cur,
                                                        qhead, qnext, uacc);
    } else {
        // fallback (fp32): own layout — bufA32, bufB32, uacc, iacc
        float* bufA32 = (float*)d_ws;
        float* bufB32 = bufA32 + (size_t)NTOT * EMB;
        float* uacc32 = bufB32 + (size_t)NTOT * EMB;
        float* iacc32 = uacc32 + (size_t)NQ * EMB;
        gather_init_kernel<<<(NQ * 16 + 255) / 256, 256, 0, stream>>>(users, items, eu, ei, uacc32, iacc32);
        init_cur_kernel<<<(NTOT * EMB / 4 + 255) / 256, 256, 0, stream>>>(eu, ei, bufA32);
        float* cur = bufA32;
        float* nxt = bufB32;
        const long long spmm_threads = (long long)NNZ * EMB;
        for (int l = 0; l < 3; ++l) {
            (void)hipMemsetAsync(nxt, 0, (size_t)NTOT * EMB * sizeof(float), stream);
            spmm_atomic_kernel<<<(int)((spmm_threads + 255) / 256), 256, 0, stream>>>(row, col, val, cur, nxt);
            gather_add_kernel<<<(NQ * 16 + 255) / 256, 256, 0, stream>>>(users, items, nxt, uacc32, iacc32);
            float* t = cur; cur = nxt; nxt = t;
        }
        dot_kernel<<<(NQ * EMB + 255) / 256, 256, 0, stream>>>(uacc32, iacc32, out);
        return;
    }

    dot_kernel<<<(NQ * EMB + 255) / 256, 256, 0, stream>>>(uacc, iacc, out);
}

// Round 21
// 222.922 us; speedup vs baseline: 1.4761x; 1.2102x over previous
//
#include <hip/hip_runtime.h>

#define NUM_USERS 100000
#define NUM_ITEMS 50000
#define NNZ       2400000
#define EMB       64
#define NTOT      (NUM_USERS + NUM_ITEMS)
#define NQ        16384
#define NBKT      ((NTOT + 255) / 256)        // 586 buckets of 256 rows
#define NAB       ((NNZ + 8191) / 8192)       // append blocks = 293 (8 edges/thread)
#define BCAP      4608                        // bucket capacity (mean 4096 + 8 sigma)
#define BCAP_LO   4096
#define SPILLCAP  32768

typedef unsigned short ushort_t;
typedef unsigned int   uint_t;

// ---------- bf16 helpers (RNE pack, exact unpack) ----------
__device__ __forceinline__ ushort_t f2bf(float f) {
    uint_t u = __float_as_uint(f);
    u += 0x7FFFu + ((u >> 16) & 1u);          // round to nearest even
    return (ushort_t)(u >> 16);
}
__device__ __forceinline__ float bf2f_lo(uint_t w) {   // low 16 bits
    return __uint_as_float(w << 16);
}
__device__ __forceinline__ float bf2f_hi(uint_t w) {   // high 16 bits
    return __uint_as_float(w & 0xFFFF0000u);
}

// ---------- nt helper (scalar element type only) ----------
__device__ __forceinline__ int2 nt_load_i2(const int2* p) {
    unsigned long long u = __builtin_nontemporal_load((const unsigned long long*)p);
    int2 r; r.x = (int)(u & 0xFFFFFFFFull); r.y = (int)(u >> 32);
    return r;
}

// gather-accumulate one edge (8 bf16 dims at octant t)
#define GACC(cc, vv) { \
    uint4 g_ = ((const uint4*)(cur + (size_t)(cc) * EMB))[t]; \
    float v_ = (vv); \
    a0 += v_ * bf2f_lo(g_.x); a1 += v_ * bf2f_hi(g_.x); \
    a2 += v_ * bf2f_lo(g_.y); a3 += v_ * bf2f_hi(g_.y); \
    a4 += v_ * bf2f_lo(g_.z); a5 += v_ * bf2f_hi(g_.z); \
    a6 += v_ * bf2f_lo(g_.w); a7 += v_ * bf2f_hi(g_.w); }

// ---------- prologue: fp32 (eu|ei) -> bf16 concat cur0 ----------
__global__ void cvt_kernel(const float* __restrict__ eu,
                           const float* __restrict__ ei,
                           ushort_t* __restrict__ cur) {
    int idx = blockIdx.x * blockDim.x + threadIdx.x;   // one float4 -> 4 bf16
    const int total4 = NTOT * EMB / 4;
    const int user4  = NUM_USERS * EMB / 4;
    if (idx >= total4) return;
    float4 v = (idx < user4) ? ((const float4*)eu)[idx]
                             : ((const float4*)ei)[idx - user4];
    uint2 o;
    o.x = (uint_t)f2bf(v.x) | ((uint_t)f2bf(v.y) << 16);
    o.y = (uint_t)f2bf(v.z) | ((uint_t)f2bf(v.w) << 16);
    ((uint2*)cur)[idx] = o;
}

// layer-0 query init (fp32 path, exact)
__global__ void gather_init_kernel(const int* __restrict__ users,
                                   const int* __restrict__ items,
                                   const float* __restrict__ eu,
                                   const float* __restrict__ ei,
                                   float* __restrict__ uacc,
                                   float* __restrict__ iacc) {
    int idx = blockIdx.x * blockDim.x + threadIdx.x;
    if (idx >= NQ * 16) return;
    int j = idx >> 4;
    int t = idx & 15;
    ((float4*)uacc)[idx] = ((const float4*)eu)[(size_t)users[j] * 16 + t];
    ((float4*)iacc)[idx] = ((const float4*)ei)[(size_t)items[j] * 16 + t];
}

__global__ void dot_kernel(const float* __restrict__ uacc,
                           const float* __restrict__ iacc,
                           float* __restrict__ out) {
    int idx = blockIdx.x * blockDim.x + threadIdx.x;
    int j = idx >> 6;
    if (j >= NQ) return;
    int d = idx & 63;
    float p = uacc[(size_t)j * EMB + d] * iacc[(size_t)j * EMB + d];
    #pragma unroll
    for (int o = 32; o > 0; o >>= 1) p += __shfl_down(p, o);
    if (d == 0) out[j] = p * (1.0f / 16.0f);
}

// ---------- one-shot init: ctr, spillcnt+qcnt, qhead ----------
__global__ void init_all_kernel(int* __restrict__ ctr,
                                int* __restrict__ cnts,    // spillcnt..qcnt (8 ints)
                                int* __restrict__ qhead) {
    int i = blockIdx.x * blockDim.x + threadIdx.x;
    if (i < NBKT) ctr[i] = 0;
    if (i < 8) cnts[i] = 0;
    if (i < NTOT) qhead[i] = -1;
}

// ---------- inverted query index + compact row list (fused) ----------
__global__ void qbuild_kernel(const int* __restrict__ users,
                              const int* __restrict__ items,
                              int* __restrict__ qhead,
                              int* __restrict__ qnext,
                              int* __restrict__ qrows,
                              int* __restrict__ qcnt) {
    int si = blockIdx.x * blockDim.x + threadIdx.x;
    if (si >= 2 * NQ) return;
    int r = (si < NQ) ? users[si] : (NUM_USERS + items[si - NQ]);
    int old = atomicExch(&qhead[r], si);
    qnext[si] = old;
    if (old < 0) {                           // first slot to touch row r
        int p = atomicAdd(qcnt, 1);
        qrows[p] = r;
    }
}

// ---------- build: LDS-aggregated fixed-capacity bucket append ----------

__global__ __launch_bounds__(1024) void append_agg_kernel(
        const int* __restrict__ row,
        const int* __restrict__ col,
        const float* __restrict__ val,
        int* __restrict__ ctr,
        int2* __restrict__ staging,
        int4* __restrict__ spill,
        int* __restrict__ spillcnt,
        int bcap) {
    __shared__ int cnt[NBKT];
    __shared__ int base[NBKT];
    int tid = threadIdx.x;
    if (tid < NBKT) cnt[tid] = 0;
    __syncthreads();

    int  myb[8], myr[8];
    int2 rec[8];
    int  rr[8], cc[8];
    int e0 = (blockIdx.x * 1024 + tid) * 8;
    bool any = (e0 < NNZ);                       // NNZ % 8 == 0 -> all-or-none
    if (any) {
        int4   r4a = *(const int4*)&row[e0];
        int4   r4b = *(const int4*)&row[e0 + 4];
        int4   c4a = *(const int4*)&col[e0];
        int4   c4b = *(const int4*)&col[e0 + 4];
        float4 v4a = *(const float4*)&val[e0];
        float4 v4b = *(const float4*)&val[e0 + 4];
        int   rs_[8] = {r4a.x, r4a.y, r4a.z, r4a.w, r4b.x, r4b.y, r4b.z, r4b.w};
        int   cs_[8] = {c4a.x, c4a.y, c4a.z, c4a.w, c4b.x, c4b.y, c4b.z, c4b.w};
        float vs_[8] = {v4a.x, v4a.y, v4a.z, v4a.w, v4b.x, v4b.y, v4b.z, v4b.w};
        #pragma unroll
        for (int j = 0; j < 8; ++j) {
            int r = rs_[j];
            int b = ((unsigned)r) >> 8;
            myb[j] = b;
            rr[j] = r; cc[j] = cs_[j];
            rec[j] = make_int2(((r & 255) << 18) | cs_[j], __float_as_int(vs_[j]));
            myr[j] = atomicAdd(&cnt[b], 1);      // local rank
        }
    }
    __syncthreads();
    if (tid < NBKT) {
        int c = cnt[tid];
        base[tid] = c ? atomicAdd(&ctr[tid], c) : 0;
    }
    __syncthreads();
    if (any) {
        #pragma unroll
        for (int j = 0; j < 8; ++j) {
            int p = base[myb[j]] + myr[j];
            if (p < bcap) {
                staging[(size_t)myb[j] * bcap + p] = rec[j];
            } else {
                int sp = atomicAdd(spillcnt, 1);
                if (sp < SPILLCAP) spill[sp] = make_int4(rr[j], cc[j], rec[j].y, 0);
            }
        }
    }
}

// ---------- within-bucket sort -> CSR (in place, fixed segments) ----------

__global__ __launch_bounds__(512) void csr_fixed_kernel(
        const int* __restrict__ ctr,
        int2* __restrict__ staging,
        int* __restrict__ rs,                    // NBKT * 257
        int bcap) {
    __shared__ int2 recs[BCAP];
    __shared__ int cnt[256];
    __shared__ int sc[256];
    __shared__ int pos[256];
    int tid = threadIdx.x;
    int b = blockIdx.x;
    int base0 = b * bcap;
    int n = min(ctr[b], bcap);

    if (tid < 256) cnt[tid] = 0;
    __syncthreads();
    for (int k = tid; k < n; k += 512) {
        int2 rec = nt_load_i2(&staging[base0 + k]);
        recs[k] = rec;
        atomicAdd(&cnt[((unsigned)rec.x) >> 18], 1);
    }
    __syncthreads();
    if (tid < 256) sc[tid] = cnt[tid];
    __syncthreads();
    #pragma unroll
    for (int o = 1; o < 256; o <<= 1) {          // Hillis-Steele inclusive scan
        int v = 0;
        if (tid < 256 && tid >= o) v = sc[tid - o];
        __syncthreads();
        if (tid < 256) sc[tid] += v;
        __syncthreads();
    }
    if (tid < 256) {
        int p = sc[tid] - cnt[tid];              // exclusive
        pos[tid] = p;
        rs[b * 257 + tid] = base0 + p;           // unconditional (phantoms: p == n)
    }
    if (tid == 0) rs[b * 257 + 256] = base0 + n;
    __syncthreads();
    for (int k = tid; k < n; k += 512) {
        int2 rec = recs[k];
        int rl = ((unsigned)rec.x) >> 18;
        int p = atomicAdd(&pos[rl], 1);
        staging[base0 + p] = make_int2(rec.x & 0x3FFFF, rec.y);
    }
}

// ---------- SpMM (two-path): one wave per row; lane = (edge-slot q 0..7, t 0..7).
// deg<=16: straight-line single 16-edge round (no loop, no extra dummies).
// deg>16:  32-edge rounds, 4 gathers in flight (2x MLP for heavy rows). ----------

__global__ __launch_bounds__(256) void spmm_csr_kernel(
        const int* __restrict__ rs,
        const int2* __restrict__ pairs,
        const ushort_t* __restrict__ cur,        // bf16 [NTOT][EMB]
        ushort_t* __restrict__ next,             // bf16 [NTOT][EMB]
        const int* __restrict__ qhead,
        const int* __restrict__ qnext,
        float* __restrict__ uacc) {              // fp32, uacc|iacc contiguous
    int gid = blockIdx.x * blockDim.x + threadIdx.x;
    int r = gid >> 6;          // wave id = row
    if (r >= NTOT) return;
    int lane = threadIdx.x & 63;
    int q = lane >> 3;         // edge slot 0..7
    int t = lane & 7;          // dim octant 0..7 (dims 8t..8t+7)
    int b = r >> 8, i = r & 255;
    int s = rs[b * 257 + i];
    int e = rs[b * 257 + i + 1];
    float a0 = 0.f, a1 = 0.f, a2 = 0.f, a3 = 0.f;
    float a4 = 0.f, a5 = 0.f, a6 = 0.f, a7 = 0.f;
    if (e - s <= 16) {
        // ---- light path: one straight-line 16-edge round ----
        int idx0 = s + q,     ok0 = idx0 < e;
        int idx1 = s + q + 8, ok1 = idx1 < e;
        int2 cv0 = nt_load_i2(&pairs[ok0 ? idx0 : s]);
        int2 cv1 = nt_load_i2(&pairs[ok1 ? idx1 : s]);
        float v0 = ok0 ? __int_as_float(cv0.y) : 0.f;
        float v1 = ok1 ? __int_as_float(cv1.y) : 0.f;
        GACC(cv0.x, v0);
        GACC(cv1.x, v1);
    } else {
        // ---- heavy path: 32-edge rounds, 4 gathers in flight ----
        for (int base = s; base < e; base += 32) {
            int   c[4];
            float v[4];
            #pragma unroll
            for (int k = 0; k < 4; ++k) {
                int idx = base + q + 8 * k;
                bool ok = idx < e;
                int2 cv = nt_load_i2(&pairs[ok ? idx : s]);
                c[k] = cv.x;
                v[k] = ok ? __int_as_float(cv.y) : 0.f;
            }
            #pragma unroll
            for (int k = 0; k < 4; ++k) GACC(c[k], v[k]);
        }
    }
    #pragma unroll
    for (int o = 8; o < 64; o <<= 1) {
        a0 += __shfl_xor(a0, o); a1 += __shfl_xor(a1, o);
        a2 += __shfl_xor(a2, o); a3 += __shfl_xor(a3, o);
        a4 += __shfl_xor(a4, o); a5 += __shfl_xor(a5, o);
        a6 += __shfl_xor(a6, o); a7 += __shfl_xor(a7, o);
    }
    if (q == 0) {
        uint4 o;
        o.x = (uint_t)f2bf(a0) | ((uint_t)f2bf(a1) << 16);
        o.y = (uint_t)f2bf(a2) | ((uint_t)f2bf(a3) << 16);
        o.z = (uint_t)f2bf(a4) | ((uint_t)f2bf(a5) << 16);
        o.w = (uint_t)f2bf(a6) | ((uint_t)f2bf(a7) << 16);
        ((uint4*)(next + (size_t)r * EMB))[t] = o;
        // fused per-layer query accumulate (fp32): lane t covers dims 8t..8t+7
        int si = qhead[r];                       // wave-uniform
        while (si >= 0) {
            float4* dst = (float4*)&uacc[(size_t)si * EMB];
            float4 d0 = dst[2 * t], d1 = dst[2 * t + 1];
            d0.x += a0; d0.y += a1; d0.z += a2; d0.w += a3;
            d1.x += a4; d1.y += a5; d1.z += a6; d1.w += a7;
            dst[2 * t] = d0; dst[2 * t + 1] = d1;
            si = qnext[si];
        }
    }
}

// ---------- last layer: only query rows (no next store, uacc accumulate only) ----

__global__ __launch_bounds__(256) void spmm_last_kernel(
        const int* __restrict__ rs,
        const int2* __restrict__ pairs,
        const ushort_t* __restrict__ cur,
        const int* __restrict__ qhead,
        const int* __restrict__ qnext,
        const int* __restrict__ qrows,
        const int* __restrict__ qcnt,
        float* __restrict__ uacc) {
    int wave = (blockIdx.x * blockDim.x + threadIdx.x) >> 6;
    if (wave >= *qcnt) return;
    int r = qrows[wave];
    int lane = threadIdx.x & 63;
    int q = lane >> 3;
    int t = lane & 7;
    int b = r >> 8, i = r & 255;
    int s = rs[b * 257 + i];
    int e = rs[b * 257 + i + 1];
    float a0 = 0.f, a1 = 0.f, a2 = 0.f, a3 = 0.f;
    float a4 = 0.f, a5 = 0.f, a6 = 0.f, a7 = 0.f;
    if (e - s <= 16) {
        int idx0 = s + q,     ok0 = idx0 < e;
        int idx1 = s + q + 8, ok1 = idx1 < e;
        int2 cv0 = nt_load_i2(&pairs[ok0 ? idx0 : s]);
        int2 cv1 = nt_load_i2(&pairs[ok1 ? idx1 : s]);
        float v0 = ok0 ? __int_as_float(cv0.y) : 0.f;
        float v1 = ok1 ? __int_as_float(cv1.y) : 0.f;
        GACC(cv0.x, v0);
        GACC(cv1.x, v1);
    } else {
        for (int base = s; base < e; base += 32) {
            int   c[4];
            float v[4];
            #pragma unroll
            for (int k = 0; k < 4; ++k) {
                int idx = base + q + 8 * k;
                bool ok = idx < e;
                int2 cv = nt_load_i2(&pairs[ok ? idx : s]);
                c[k] = cv.x;
                v[k] = ok ? __int_as_float(cv.y) : 0.f;
            }
            #pragma unroll
            for (int k = 0; k < 4; ++k) GACC(c[k], v[k]);
        }
    }
    #pragma unroll
    for (int o = 8; o < 64; o <<= 1) {
        a0 += __shfl_xor(a0, o); a1 += __shfl_xor(a1, o);
        a2 += __shfl_xor(a2, o); a3 += __shfl_xor(a3, o);
        a4 += __shfl_xor(a4, o); a5 += __shfl_xor(a5, o);
        a6 += __shfl_xor(a6, o); a7 += __shfl_xor(a7, o);
    }
    if (q == 0) {
        int si = qhead[r];
        while (si >= 0) {
            float4* dst = (float4*)&uacc[(size_t)si * EMB];
            float4 d0 = dst[2 * t], d1 = dst[2 * t + 1];
            d0.x += a0; d0.y += a1; d0.z += a2; d0.w += a3;
            d1.x += a4; d1.y += a5; d1.z += a6; d1.w += a7;
            dst[2 * t] = d0; dst[2 * t + 1] = d1;
            si = qnext[si];
        }
    }
}

// spill edges (statically ~unreachable): CAS on bf16 pair of next
__global__ void spill_apply_kernel(const int4* __restrict__ spill,
                                   const int* __restrict__ spillcnt,
                                   const ushort_t* __restrict__ cur,
                                   ushort_t* __restrict__ next) {
    int n = min(*spillcnt, SPILLCAP);
    for (int idx = blockIdx.x * blockDim.x + threadIdx.x;
         idx < n * 32; idx += gridDim.x * blockDim.x) {
        int e = idx >> 5, w = idx & 31;          // word w covers dims 2w, 2w+1
        int4 rec = spill[e];
        float v = __int_as_float(rec.z);
        float g0 = bf2f_lo((uint_t)cur[(size_t)rec.y * EMB + 2 * w]);
        float g1 = bf2f_lo((uint_t)cur[(size_t)rec.y * EMB + 2 * w + 1]);
        uint_t* addr = (uint_t*)(next + (size_t)rec.x * EMB + 2 * w);
        uint_t old = *addr, assumed;
        do {
            assumed = old;
            float o0 = bf2f_lo(assumed);
            float o1 = bf2f_hi(assumed);
            uint_t nw = (uint_t)f2bf(o0 + v * g0) | ((uint_t)f2bf(o1 + v * g1) << 16);
            old = atomicCAS(addr, assumed, nw);
        } while (old != assumed);
    }
}

// last-layer spill (statically ~unreachable): add into uacc via query chain
__global__ void spill_apply_last_kernel(const int4* __restrict__ spill,
                                        const int* __restrict__ spillcnt,
                                        const ushort_t* __restrict__ cur,
                                        const int* __restrict__ qhead,
                                        const int* __restrict__ qnext,
                                        float* __restrict__ uacc) {
    int n = min(*spillcnt, SPILLCAP);
    for (int idx = blockIdx.x * blockDim.x + threadIdx.x;
         idx < n * EMB; idx += gridDim.x * blockDim.x) {
        int e = idx >> 6, d = idx & 63;
        int4 rec = spill[e];
        float v = __int_as_float(rec.z);
        float g = bf2f_lo((uint_t)cur[(size_t)rec.y * EMB + d]);
        int si = qhead[rec.x];
        while (si >= 0) {
            atomicAdd(&uacc[(size_t)si * EMB + d], v * g);
            si = qnext[si];
        }
    }
}

// ---------- fallback path (ws too small): fp32 atomic SpMM ----------

__global__ void init_cur_kernel(const float* __restrict__ eu,
                                const float* __restrict__ ei,
                                float* __restrict__ cur) {
    int idx = blockIdx.x * blockDim.x + threadIdx.x;
    const int total4 = NTOT * EMB / 4;
    const int user4  = NUM_USERS * EMB / 4;
    if (idx < total4) {
        float4 v;
        if (idx < user4) v = ((const float4*)eu)[idx];
        else             v = ((const float4*)ei)[idx - user4];
        ((float4*)cur)[idx] = v;
    }
}

__global__ void gather_add_kernel(const int* __restrict__ users,
                                  const int* __restrict__ items,
                                  const float* __restrict__ src,
                                  float* __restrict__ uacc,
                                  float* __restrict__ iacc) {
    int idx = blockIdx.x * blockDim.x + threadIdx.x;
    if (idx >= NQ * 16) return;
    int j = idx >> 4;
    int t = idx & 15;
    float4 uv = ((const float4*)src)[(size_t)users[j] * 16 + t];
    float4 iv = ((const float4*)src)[(size_t)(NUM_USERS + items[j]) * 16 + t];
    float4* up = (float4*)uacc + idx;
    float4* ip = (float4*)iacc + idx;
    float4 a = *up, b = *ip;
    a.x += uv.x; a.y += uv.y; a.z += uv.z; a.w += uv.w;
    b.x += iv.x; b.y += iv.y; b.z += iv.z; b.w += iv.w;
    *up = a; *ip = b;
}

__global__ void spmm_atomic_kernel(const int* __restrict__ row,
                                   const int* __restrict__ col,
                                   const float* __restrict__ val,
                                   const float* __restrict__ cur,
                                   float* __restrict__ next) {
    long long idx = (long long)blockIdx.x * blockDim.x + threadIdx.x;
    if (idx >= (long long)NNZ * EMB) return;
    int e = (int)(idx >> 6);
    int d = (int)(idx & 63);
    atomicAdd(&next[row[e] * EMB + d], val[e] * cur[col[e] * EMB + d]);
}

extern "C" void kernel_launch(void* const* d_in, const int* in_sizes, int n_in,
                              void* d_out, int out_size, void* d_ws, size_t ws_size,
                              hipStream_t stream) {
    const int*   row   = (const int*)d_in[0];
    const int*   col   = (const int*)d_in[1];
    const float* val   = (const float*)d_in[2];
    const float* eu    = (const float*)d_in[3];
    const float* ei    = (const float*)d_in[4];
    const int*   users = (const int*)d_in[5];
    const int*   items = (const int*)d_in[6];
    float*       out   = (float*)d_out;

    // primary workspace layout (bf16 layer buffers)
    ushort_t* bufA = (ushort_t*)d_ws;                    // NTOT*EMB bf16
    ushort_t* bufB = bufA + (size_t)NTOT * EMB;          // NTOT*EMB bf16
    float* uacc = (float*)(bufB + (size_t)NTOT * EMB);   // NQ*EMB f32
    float* iacc = uacc + (size_t)NQ * EMB;               // NQ*EMB f32 (contiguous!)
    int*   ctr  = (int*)(iacc + (size_t)NQ * EMB);       // NBKT
    int*   rs   = ctr + NBKT;                            // NBKT*257
    int*   spillcnt = rs + NBKT * 257;                   // 4
    int*   qcnt = spillcnt + 4;                          // 4
    int*   qhead = qcnt + 4;                             // NTOT
    int*   qnext = qhead + NTOT;                         // 2*NQ
    int*   qrows = qnext + 2 * NQ;                       // 2*NQ
    int4*  spill = (int4*)(qrows + 2 * NQ);              // SPILLCAP
    int2*  staging = (int2*)(spill + SPILLCAP);          // NBKT*bcap

    size_t fixed_bytes = (size_t)((char*)staging - (char*)d_ws);
    size_t needHi = fixed_bytes + (size_t)NBKT * BCAP * sizeof(int2);
    size_t needLo = fixed_bytes + (size_t)NBKT * BCAP_LO * sizeof(int2);
    int bcap = (ws_size >= needHi) ? BCAP : ((ws_size >= needLo) ? BCAP_LO : 0);

    if (bcap > 0) {
        gather_init_kernel<<<(NQ * 16 + 255) / 256, 256, 0, stream>>>(users, items, eu, ei, uacc, iacc);
        cvt_kernel<<<(NTOT * 16 + 255) / 256, 256, 0, stream>>>(eu, ei, bufA);
        init_all_kernel<<<(NTOT + 255) / 256, 256, 0, stream>>>(ctr, spillcnt, qhead);
        qbuild_kernel<<<(2 * NQ + 255) / 256, 256, 0, stream>>>(users, items, qhead, qnext, qrows, qcnt);
        append_agg_kernel<<<NAB, 1024, 0, stream>>>(row, col, val, ctr, staging,
                                                    spill, spillcnt, bcap);
        csr_fixed_kernel<<<NBKT, 512, 0, stream>>>(ctr, staging, rs, bcap);

        ushort_t* cur = bufA;
        ushort_t* nxt = bufB;
        for (int l = 0; l < 2; ++l) {
            spmm_csr_kernel<<<(NTOT * 64 + 255) / 256, 256, 0, stream>>>(
                rs, staging, cur, nxt, qhead, qnext, uacc);
            spill_apply_kernel<<<64, 256, 0, stream>>>(spill, spillcnt, cur, nxt);
            ushort_t* tmp = cur; cur = nxt; nxt = tmp;
        }
        // last layer: only rows consumed by query chains; no next store
        spmm_last_kernel<<<(2 * NQ * 64 + 255) / 256, 256, 0, stream>>>(
            rs, staging, cur, qhead, qnext, qrows, qcnt, uacc);
        spill_apply_last_kernel<<<64, 256, 0, stream>>>(spill, spillcnt, cur,
                                                        qhead, qnext, uacc);
    } else {
        // fallback (fp32): own layout — bufA32, bufB32, uacc, iacc
        float* bufA32 = (float*)d_ws;
        float* bufB32 = bufA32 + (size_t)NTOT * EMB;
        float* uacc32 = bufB32 + (size_t)NTOT * EMB;
        float* iacc32 = uacc32 + (size_t)NQ * EMB;
        gather_init_kernel<<<(NQ * 16 + 255) / 256, 256, 0, stream>>>(users, items, eu, ei, uacc32, iacc32);
        init_cur_kernel<<<(NTOT * EMB / 4 + 255) / 256, 256, 0, stream>>>(eu, ei, bufA32);
        float* cur = bufA32;
        float* nxt = bufB32;
        const long long spmm_threads = (long long)NNZ * EMB;
        for (int l = 0; l < 3; ++l) {
            (void)hipMemsetAsync(nxt, 0, (size_t)NTOT * EMB * sizeof(float), stream);
            spmm_atomic_kernel<<<(int)((spmm_threads + 255) / 256), 256, 0, stream>>>(row, col, val, cur, nxt);
            gather_add_kernel<<<(NQ * 16 + 255) / 256, 256, 0, stream>>>(users, items, nxt, uacc32, iacc32);
            float* t = cur; cur = nxt; nxt = t;
        }
        dot_kernel<<<(NQ * EMB + 255) / 256, 256, 0, stream>>>(uacc32, iacc32, out);
        return;
    }

    dot_kernel<<<(NQ * EMB + 255) / 256, 256, 0, stream>>>(uacc, iacc, out);
}

// Round 22
// 216.718 us; speedup vs baseline: 1.5184x; 1.0286x over previous
//
#include <hip/hip_runtime.h>

#define NUM_USERS 100000
#define NUM_ITEMS 50000
#define NNZ       2400000
#define EMB       64
#define NTOT      (NUM_USERS + NUM_ITEMS)
#define NQ        16384
#define NBKT      ((NTOT + 255) / 256)        // 586 buckets of 256 rows
#define NAB       ((NNZ + 8191) / 8192)       // append blocks = 293 (8 edges/thread)
#define BCAP      4608                        // bucket capacity (mean 4096 + 8 sigma)
#define BCAP_LO   4096
#define SPILLCAP  32768

typedef unsigned short ushort_t;
typedef unsigned int   uint_t;

// ---------- bf16 helpers (RNE pack, exact unpack) ----------
__device__ __forceinline__ ushort_t f2bf(float f) {
    uint_t u = __float_as_uint(f);
    u += 0x7FFFu + ((u >> 16) & 1u);          // round to nearest even
    return (ushort_t)(u >> 16);
}
__device__ __forceinline__ float bf2f_lo(uint_t w) {   // low 16 bits
    return __uint_as_float(w << 16);
}
__device__ __forceinline__ float bf2f_hi(uint_t w) {   // high 16 bits
    return __uint_as_float(w & 0xFFFF0000u);
}

// ---------- nt helper (scalar element type only) ----------
__device__ __forceinline__ int2 nt_load_i2(const int2* p) {
    unsigned long long u = __builtin_nontemporal_load((const unsigned long long*)p);
    int2 r; r.x = (int)(u & 0xFFFFFFFFull); r.y = (int)(u >> 32);
    return r;
}

// gather-accumulate one edge (8 bf16 dims at octant t)
#define GACC(cc, vv) { \
    uint4 g_ = ((const uint4*)(cur + (size_t)(cc) * EMB))[t]; \
    float v_ = (vv); \
    a0 += v_ * bf2f_lo(g_.x); a1 += v_ * bf2f_hi(g_.x); \
    a2 += v_ * bf2f_lo(g_.y); a3 += v_ * bf2f_hi(g_.y); \
    a4 += v_ * bf2f_lo(g_.z); a5 += v_ * bf2f_hi(g_.z); \
    a6 += v_ * bf2f_lo(g_.w); a7 += v_ * bf2f_hi(g_.w); }

// ---------- fused prologue: cvt + layer-0 query init + counter/qhead init ----------
__global__ void prologue_kernel(const float* __restrict__ eu,
                                const float* __restrict__ ei,
                                const int* __restrict__ users,
                                const int* __restrict__ items,
                                ushort_t* __restrict__ cur,
                                float* __restrict__ uacc,
                                float* __restrict__ iacc,
                                int* __restrict__ ctr,
                                int* __restrict__ cnts,
                                int* __restrict__ qhead) {
    int idx = blockIdx.x * blockDim.x + threadIdx.x;
    const int total4 = NTOT * EMB / 4;                 // 2.4M
    const int user4  = NUM_USERS * EMB / 4;
    if (idx < total4) {                                 // fp32 -> bf16 concat
        float4 v = (idx < user4) ? ((const float4*)eu)[idx]
                                 : ((const float4*)ei)[idx - user4];
        uint2 o;
        o.x = (uint_t)f2bf(v.x) | ((uint_t)f2bf(v.y) << 16);
        o.y = (uint_t)f2bf(v.z) | ((uint_t)f2bf(v.w) << 16);
        ((uint2*)cur)[idx] = o;
    }
    if (idx < NQ * 16) {                                // layer-0 query gather (fp32)
        int j = idx >> 4;
        int t = idx & 15;
        ((float4*)uacc)[idx] = ((const float4*)eu)[(size_t)users[j] * 16 + t];
        ((float4*)iacc)[idx] = ((const float4*)ei)[(size_t)items[j] * 16 + t];
    }
    if (idx < NTOT) qhead[idx] = -1;
    if (idx < NBKT) ctr[idx] = 0;
    if (idx < 8)    cnts[idx] = 0;
}

__global__ void dot_kernel(const float* __restrict__ uacc,
                           const float* __restrict__ iacc,
                           float* __restrict__ out) {
    int idx = blockIdx.x * blockDim.x + threadIdx.x;
    int j = idx >> 6;
    if (j >= NQ) return;
    int d = idx & 63;
    float p = uacc[(size_t)j * EMB + d] * iacc[(size_t)j * EMB + d];
    #pragma unroll
    for (int o = 32; o > 0; o >>= 1) p += __shfl_down(p, o);
    if (d == 0) out[j] = p * (1.0f / 16.0f);
}

// ---------- inverted query index + compact row list (fused) ----------
__global__ void qbuild_kernel(const int* __restrict__ users,
                              const int* __restrict__ items,
                              int* __restrict__ qhead,
                              int* __restrict__ qnext,
                              int* __restrict__ qrows,
                              int* __restrict__ qcnt) {
    int si = blockIdx.x * blockDim.x + threadIdx.x;
    if (si >= 2 * NQ) return;
    int r = (si < NQ) ? users[si] : (NUM_USERS + items[si - NQ]);
    int old = atomicExch(&qhead[r], si);
    qnext[si] = old;
    if (old < 0) {                           // first slot to touch row r
        int p = atomicAdd(qcnt, 1);
        qrows[p] = r;
    }
}

// ---------- build: LDS-aggregated fixed-capacity bucket append ----------

__global__ __launch_bounds__(1024) void append_agg_kernel(
        const int* __restrict__ row,
        const int* __restrict__ col,
        const float* __restrict__ val,
        int* __restrict__ ctr,
        int2* __restrict__ staging,
        int4* __restrict__ spill,
        int* __restrict__ spillcnt,
        int bcap) {
    __shared__ int cnt[NBKT];
    __shared__ int base[NBKT];
    int tid = threadIdx.x;
    if (tid < NBKT) cnt[tid] = 0;
    __syncthreads();

    int  myb[8], myr[8];
    int2 rec[8];
    int  rr[8], cc[8];
    int e0 = (blockIdx.x * 1024 + tid) * 8;
    bool any = (e0 < NNZ);                       // NNZ % 8 == 0 -> all-or-none
    if (any) {
        int4   r4a = *(const int4*)&row[e0];
        int4   r4b = *(const int4*)&row[e0 + 4];
        int4   c4a = *(const int4*)&col[e0];
        int4   c4b = *(const int4*)&col[e0 + 4];
        float4 v4a = *(const float4*)&val[e0];
        float4 v4b = *(const float4*)&val[e0 + 4];
        int   rs_[8] = {r4a.x, r4a.y, r4a.z, r4a.w, r4b.x, r4b.y, r4b.z, r4b.w};
        int   cs_[8] = {c4a.x, c4a.y, c4a.z, c4a.w, c4b.x, c4b.y, c4b.z, c4b.w};
        float vs_[8] = {v4a.x, v4a.y, v4a.z, v4a.w, v4b.x, v4b.y, v4b.z, v4b.w};
        #pragma unroll
        for (int j = 0; j < 8; ++j) {
            int r = rs_[j];
            int b = ((unsigned)r) >> 8;
            myb[j] = b;
            rr[j] = r; cc[j] = cs_[j];
            rec[j] = make_int2(((r & 255) << 18) | cs_[j], __float_as_int(vs_[j]));
            myr[j] = atomicAdd(&cnt[b], 1);      // local rank
        }
    }
    __syncthreads();
    if (tid < NBKT) {
        int c = cnt[tid];
        base[tid] = c ? atomicAdd(&ctr[tid], c) : 0;
    }
    __syncthreads();
    if (any) {
        #pragma unroll
        for (int j = 0; j < 8; ++j) {
            int p = base[myb[j]] + myr[j];
            if (p < bcap) {
                staging[(size_t)myb[j] * bcap + p] = rec[j];
            } else {
                int sp = atomicAdd(spillcnt, 1);
                if (sp < SPILLCAP) spill[sp] = make_int4(rr[j], cc[j], rec[j].y, 0);
            }
        }
    }
}

// ---------- within-bucket sort -> CSR (in place, fixed segments) ----------

__global__ __launch_bounds__(512) void csr_fixed_kernel(
        const int* __restrict__ ctr,
        int2* __restrict__ staging,
        int* __restrict__ rs,                    // NBKT * 257
        int bcap) {
    __shared__ int2 recs[BCAP];
    __shared__ int cnt[256];
    __shared__ int sc[256];
    __shared__ int pos[256];
    int tid = threadIdx.x;
    int b = blockIdx.x;
    int base0 = b * bcap;
    int n = min(ctr[b], bcap);

    if (tid < 256) cnt[tid] = 0;
    __syncthreads();
    for (int k = tid; k < n; k += 512) {
        int2 rec = nt_load_i2(&staging[base0 + k]);
        recs[k] = rec;
        atomicAdd(&cnt[((unsigned)rec.x) >> 18], 1);
    }
    __syncthreads();
    if (tid < 256) sc[tid] = cnt[tid];
    __syncthreads();
    #pragma unroll
    for (int o = 1; o < 256; o <<= 1) {          // Hillis-Steele inclusive scan
        int v = 0;
        if (tid < 256 && tid >= o) v = sc[tid - o];
        __syncthreads();
        if (tid < 256) sc[tid] += v;
        __syncthreads();
    }
    if (tid < 256) {
        int p = sc[tid] - cnt[tid];              // exclusive
        pos[tid] = p;
        rs[b * 257 + tid] = base0 + p;           // unconditional (phantoms: p == n)
    }
    if (tid == 0) rs[b * 257 + 256] = base0 + n;
    __syncthreads();
    for (int k = tid; k < n; k += 512) {
        int2 rec = recs[k];
        int rl = ((unsigned)rec.x) >> 18;
        int p = atomicAdd(&pos[rl], 1);
        staging[base0 + p] = make_int2(rec.x & 0x3FFFF, rec.y);
    }
}

// ---------- SpMM (two-path): one wave per row; lane = (edge-slot q 0..7, t 0..7) ----

__global__ __launch_bounds__(256) void spmm_csr_kernel(
        const int* __restrict__ rs,
        const int2* __restrict__ pairs,
        const ushort_t* __restrict__ cur,        // bf16 [NTOT][EMB]
        ushort_t* __restrict__ next,             // bf16 [NTOT][EMB]
        const int* __restrict__ qhead,
        const int* __restrict__ qnext,
        float* __restrict__ uacc) {              // fp32, uacc|iacc contiguous
    int gid = blockIdx.x * blockDim.x + threadIdx.x;
    int r = gid >> 6;          // wave id = row
    if (r >= NTOT) return;
    int lane = threadIdx.x & 63;
    int q = lane >> 3;         // edge slot 0..7
    int t = lane & 7;          // dim octant 0..7 (dims 8t..8t+7)
    int b = r >> 8, i = r & 255;
    int s = rs[b * 257 + i];
    int e = rs[b * 257 + i + 1];
    float a0 = 0.f, a1 = 0.f, a2 = 0.f, a3 = 0.f;
    float a4 = 0.f, a5 = 0.f, a6 = 0.f, a7 = 0.f;
    if (e - s <= 16) {
        // ---- light path: one straight-line 16-edge round ----
        int idx0 = s + q,     ok0 = idx0 < e;
        int idx1 = s + q + 8, ok1 = idx1 < e;
        int2 cv0 = nt_load_i2(&pairs[ok0 ? idx0 : s]);
        int2 cv1 = nt_load_i2(&pairs[ok1 ? idx1 : s]);
        float v0 = ok0 ? __int_as_float(cv0.y) : 0.f;
        float v1 = ok1 ? __int_as_float(cv1.y) : 0.f;
        GACC(cv0.x, v0);
        GACC(cv1.x, v1);
    } else {
        // ---- heavy path: 32-edge rounds, 4 gathers in flight ----
        for (int base = s; base < e; base += 32) {
            int   c[4];
            float v[4];
            #pragma unroll
            for (int k = 0; k < 4; ++k) {
                int idx = base + q + 8 * k;
                bool ok = idx < e;
                int2 cv = nt_load_i2(&pairs[ok ? idx : s]);
                c[k] = cv.x;
                v[k] = ok ? __int_as_float(cv.y) : 0.f;
            }
            #pragma unroll
            for (int k = 0; k < 4; ++k) GACC(c[k], v[k]);
        }
    }
    #pragma unroll
    for (int o = 8; o < 64; o <<= 1) {
        a0 += __shfl_xor(a0, o); a1 += __shfl_xor(a1, o);
        a2 += __shfl_xor(a2, o); a3 += __shfl_xor(a3, o);
        a4 += __shfl_xor(a4, o); a5 += __shfl_xor(a5, o);
        a6 += __shfl_xor(a6, o); a7 += __shfl_xor(a7, o);
    }
    if (q == 0) {
        uint4 o;
        o.x = (uint_t)f2bf(a0) | ((uint_t)f2bf(a1) << 16);
        o.y = (uint_t)f2bf(a2) | ((uint_t)f2bf(a3) << 16);
        o.z = (uint_t)f2bf(a4) | ((uint_t)f2bf(a5) << 16);
        o.w = (uint_t)f2bf(a6) | ((uint_t)f2bf(a7) << 16);
        ((uint4*)(next + (size_t)r * EMB))[t] = o;
        // fused per-layer query accumulate (fp32): lane t covers dims 8t..8t+7
        int si = qhead[r];                       // wave-uniform
        while (si >= 0) {
            float4* dst = (float4*)&uacc[(size_t)si * EMB];
            float4 d0 = dst[2 * t], d1 = dst[2 * t + 1];
            d0.x += a0; d0.y += a1; d0.z += a2; d0.w += a3;
            d1.x += a4; d1.y += a5; d1.z += a6; d1.w += a7;
            dst[2 * t] = d0; dst[2 * t + 1] = d1;
            si = qnext[si];
        }
    }
}

// ---------- last layer: only query rows (no next store, uacc accumulate only) ----

__global__ __launch_bounds__(256) void spmm_last_kernel(
        const int* __restrict__ rs,
        const int2* __restrict__ pairs,
        const ushort_t* __restrict__ cur,
        const int* __restrict__ qhead,
        const int* __restrict__ qnext,
        const int* __restrict__ qrows,
        const int* __restrict__ qcnt,
        float* __restrict__ uacc) {
    int wave = (blockIdx.x * blockDim.x + threadIdx.x) >> 6;
    if (wave >= *qcnt) return;
    int r = qrows[wave];
    int lane = threadIdx.x & 63;
    int q = lane >> 3;
    int t = lane & 7;
    int b = r >> 8, i = r & 255;
    int s = rs[b * 257 + i];
    int e = rs[b * 257 + i + 1];
    float a0 = 0.f, a1 = 0.f, a2 = 0.f, a3 = 0.f;
    float a4 = 0.f, a5 = 0.f, a6 = 0.f, a7 = 0.f;
    if (e - s <= 16) {
        int idx0 = s + q,     ok0 = idx0 < e;
        int idx1 = s + q + 8, ok1 = idx1 < e;
        int2 cv0 = nt_load_i2(&pairs[ok0 ? idx0 : s]);
        int2 cv1 = nt_load_i2(&pairs[ok1 ? idx1 : s]);
        float v0 = ok0 ? __int_as_float(cv0.y) : 0.f;
        float v1 = ok1 ? __int_as_float(cv1.y) : 0.f;
        GACC(cv0.x, v0);
        GACC(cv1.x, v1);
    } else {
        for (int base = s; base < e; base += 32) {
            int   c[4];
            float v[4];
            #pragma unroll
            for (int k = 0; k < 4; ++k) {
                int idx = base + q + 8 * k;
                bool ok = idx < e;
                int2 cv = nt_load_i2(&pairs[ok ? idx : s]);
                c[k] = cv.x;
                v[k] = ok ? __int_as_float(cv.y) : 0.f;
            }
            #pragma unroll
            for (int k = 0; k < 4; ++k) GACC(c[k], v[k]);
        }
    }
    #pragma unroll
    for (int o = 8; o < 64; o <<= 1) {
        a0 += __shfl_xor(a0, o); a1 += __shfl_xor(a1, o);
        a2 += __shfl_xor(a2, o); a3 += __shfl_xor(a3, o);
        a4 += __shfl_xor(a4, o); a5 += __shfl_xor(a5, o);
        a6 += __shfl_xor(a6, o); a7 += __shfl_xor(a7, o);
    }
    if (q == 0) {
        int si = qhead[r];
        while (si >= 0) {
            float4* dst = (float4*)&uacc[(size_t)si * EMB];
            float4 d0 = dst[2 * t], d1 = dst[2 * t + 1];
            d0.x += a0; d0.y += a1; d0.z += a2; d0.w += a3;
            d1.x += a4; d1.y += a5; d1.z += a6; d1.w += a7;
            dst[2 * t] = d0; dst[2 * t + 1] = d1;
            si = qnext[si];
        }
    }
}

// spill edges (statically ~unreachable): CAS on bf16 pair of next
__global__ void spill_apply_kernel(const int4* __restrict__ spill,
                                   const int* __restrict__ spillcnt,
                                   const ushort_t* __restrict__ cur,
                                   ushort_t* __restrict__ next) {
    int n = min(*spillcnt, SPILLCAP);
    for (int idx = blockIdx.x * blockDim.x + threadIdx.x;
         idx < n * 32; idx += gridDim.x * blockDim.x) {
        int e = idx >> 5, w = idx & 31;          // word w covers dims 2w, 2w+1
        int4 rec = spill[e];
        float v = __int_as_float(rec.z);
        float g0 = bf2f_lo((uint_t)cur[(size_t)rec.y * EMB + 2 * w]);
        float g1 = bf2f_lo((uint_t)cur[(size_t)rec.y * EMB + 2 * w + 1]);
        uint_t* addr = (uint_t*)(next + (size_t)rec.x * EMB + 2 * w);
        uint_t old = *addr, assumed;
        do {
            assumed = old;
            float o0 = bf2f_lo(assumed);
            float o1 = bf2f_hi(assumed);
            uint_t nw = (uint_t)f2bf(o0 + v * g0) | ((uint_t)f2bf(o1 + v * g1) << 16);
            old = atomicCAS(addr, assumed, nw);
        } while (old != assumed);
    }
}

// last-layer spill (statically ~unreachable): add into uacc via query chain
__global__ void spill_apply_last_kernel(const int4* __restrict__ spill,
                                        const int* __restrict__ spillcnt,
                                        const ushort_t* __restrict__ cur,
                                        const int* __restrict__ qhead,
                                        const int* __restrict__ qnext,
                                        float* __restrict__ uacc) {
    int n = min(*spillcnt, SPILLCAP);
    for (int idx = blockIdx.x * blockDim.x + threadIdx.x;
         idx < n * EMB; idx += gridDim.x * blockDim.x) {
        int e = idx >> 6, d = idx & 63;
        int4 rec = spill[e];
        float v = __int_as_float(rec.z);
        float g = bf2f_lo((uint_t)cur[(size_t)rec.y * EMB + d]);
        int si = qhead[rec.x];
        while (si >= 0) {
            atomicAdd(&uacc[(size_t)si * EMB + d], v * g);
            si = qnext[si];
        }
    }
}

// ---------- fallback path (ws too small): fp32 atomic SpMM ----------

__global__ void init_cur_kernel(const float* __restrict__ eu,
                                const float* __restrict__ ei,
                                float* __restrict__ cur) {
    int idx = blockIdx.x * blockDim.x + threadIdx.x;
    const int total4 = NTOT * EMB / 4;
    const int user4  = NUM_USERS * EMB / 4;
    if (idx < total4) {
        float4 v;
        if (idx < user4) v = ((const float4*)eu)[idx];
        else             v = ((const float4*)ei)[idx - user4];
        ((float4*)cur)[idx] = v;
    }
}

__global__ void gather_init32_kernel(const int* __restrict__ users,
                                     const int* __restrict__ items,
                                     const float* __restrict__ eu,
                                     const float* __restrict__ ei,
                                     float* __restrict__ uacc,
                                     float* __restrict__ iacc) {
    int idx = blockIdx.x * blockDim.x + threadIdx.x;
    if (idx >= NQ * 16) return;
    int j = idx >> 4;
    int t = idx & 15;
    ((float4*)uacc)[idx] = ((const float4*)eu)[(size_t)users[j] * 16 + t];
    ((float4*)iacc)[idx] = ((const float4*)ei)[(size_t)items[j] * 16 + t];
}

__global__ void gather_add_kernel(const int* __restrict__ users,
                                  const int* __restrict__ items,
                                  const float* __restrict__ src,
                                  float* __restrict__ uacc,
                                  float* __restrict__ iacc) {
    int idx = blockIdx.x * blockDim.x + threadIdx.x;
    if (idx >= NQ * 16) return;
    int j = idx >> 4;
    int t = idx & 15;
    float4 uv = ((const float4*)src)[(size_t)users[j] * 16 + t];
    float4 iv = ((const float4*)src)[(size_t)(NUM_USERS + items[j]) * 16 + t];
    float4* up = (float4*)uacc + idx;
    float4* ip = (float4*)iacc + idx;
    float4 a = *up, b = *ip;
    a.x += uv.x; a.y += uv.y; a.z += uv.z; a.w += uv.w;
    b.x += iv.x; b.y += iv.y; b.z += iv.z; b.w += iv.w;
    *up = a; *ip = b;
}

__global__ void spmm_atomic_kernel(const int* __restrict__ row,
                                   const int* __restrict__ col,
                                   const float* __restrict__ val,
                                   const float* __restrict__ cur,
                                   float* __restrict__ next) {
    long long idx = (long long)blockIdx.x * blockDim.x + threadIdx.x;
    if (idx >= (long long)NNZ * EMB) return;
    int e = (int)(idx >> 6);
    int d = (int)(idx & 63);
    atomicAdd(&next[row[e] * EMB + d], val[e] * cur[col[e] * EMB + d]);
}

extern "C" void kernel_launch(void* const* d_in, const int* in_sizes, int n_in,
                              void* d_out, int out_size, void* d_ws, size_t ws_size,
                              hipStream_t stream) {
    const int*   row   = (const int*)d_in[0];
    const int*   col   = (const int*)d_in[1];
    const float* val   = (const float*)d_in[2];
    const float* eu    = (const float*)d_in[3];
    const float* ei    = (const float*)d_in[4];
    const int*   users = (const int*)d_in[5];
    const int*   items = (const int*)d_in[6];
    float*       out   = (float*)d_out;

    // primary workspace layout (bf16 layer buffers)
    ushort_t* bufA = (ushort_t*)d_ws;                    // NTOT*EMB bf16
    ushort_t* bufB = bufA + (size_t)NTOT * EMB;          // NTOT*EMB bf16
    float* uacc = (float*)(bufB + (size_t)NTOT * EMB);   // NQ*EMB f32
    float* iacc = uacc + (size_t)NQ * EMB;               // NQ*EMB f32 (contiguous!)
    int*   ctr  = (int*)(iacc + (size_t)NQ * EMB);       // NBKT
    int*   rs   = ctr + NBKT;                            // NBKT*257
    int*   spillcnt = rs + NBKT * 257;                   // 4
    int*   qcnt = spillcnt + 4;                          // 4
    int*   qhead = qcnt + 4;                             // NTOT
    int*   qnext = qhead + NTOT;                         // 2*NQ
    int*   qrows = qnext + 2 * NQ;                       // 2*NQ
    int4*  spill = (int4*)(qrows + 2 * NQ);              // SPILLCAP
    int2*  staging = (int2*)(spill + SPILLCAP);          // NBKT*bcap

    size_t fixed_bytes = (size_t)((char*)staging - (char*)d_ws);
    size_t needHi = fixed_bytes + (size_t)NBKT * BCAP * sizeof(int2);
    size_t needLo = fixed_bytes + (size_t)NBKT * BCAP_LO * sizeof(int2);
    int bcap = (ws_size >= needHi) ? BCAP : ((ws_size >= needLo) ? BCAP_LO : 0);

    if (bcap > 0) {
        prologue_kernel<<<(NTOT * 16 + 255) / 256, 256, 0, stream>>>(
            eu, ei, users, items, bufA, uacc, iacc, ctr, spillcnt, qhead);
        qbuild_kernel<<<(2 * NQ + 255) / 256, 256, 0, stream>>>(users, items, qhead, qnext, qrows, qcnt);
        append_agg_kernel<<<NAB, 1024, 0, stream>>>(row, col, val, ctr, staging,
                                                    spill, spillcnt, bcap);
        csr_fixed_kernel<<<NBKT, 512, 0, stream>>>(ctr, staging, rs, bcap);

        ushort_t* cur = bufA;
        ushort_t* nxt = bufB;
        for (int l = 0; l < 2; ++l) {
            spmm_csr_kernel<<<(NTOT * 64 + 255) / 256, 256, 0, stream>>>(
                rs, staging, cur, nxt, qhead, qnext, uacc);
            spill_apply_kernel<<<4, 256, 0, stream>>>(spill, spillcnt, cur, nxt);
            ushort_t* tmp = cur; cur = nxt; nxt = tmp;
        }
        // last layer: only rows consumed by query chains; no next store
        spmm_last_kernel<<<(2 * NQ * 64 + 255) / 256, 256, 0, stream>>>(
            rs, staging, cur, qhead, qnext, qrows, qcnt, uacc);
        spill_apply_last_kernel<<<4, 256, 0, stream>>>(spill, spillcnt, cur,
                                                       qhead, qnext, uacc);
    } else {
        // fallback (fp32): own layout — bufA32, bufB32, uacc, iacc
        float* bufA32 = (float*)d_ws;
        float* bufB32 = bufA32 + (size_t)NTOT * EMB;
        float* uacc32 = bufB32 + (size_t)NTOT * EMB;
        float* iacc32 = uacc32 + (size_t)NQ * EMB;
        gather_init32_kernel<<<(NQ * 16 + 255) / 256, 256, 0, stream>>>(users, items, eu, ei, uacc32, iacc32);
        init_cur_kernel<<<(NTOT * EMB / 4 + 255) / 256, 256, 0, stream>>>(eu, ei, bufA32);
        float* cur = bufA32;
        float* nxt = bufB32;
        const long long spmm_threads = (long long)NNZ * EMB;
        for (int l = 0; l < 3; ++l) {
            (void)hipMemsetAsync(nxt, 0, (size_t)NTOT * EMB * sizeof(float), stream);
            spmm_atomic_kernel<<<(int)((spmm_threads + 255) / 256), 256, 0, stream>>>(row, col, val, cur, nxt);
            gather_add_kernel<<<(NQ * 16 + 255) / 256, 256, 0, stream>>>(users, items, nxt, uacc32, iacc32);
            float* t = cur; cur = nxt; nxt = t;
        }
        dot_kernel<<<(NQ * EMB + 255) / 256, 256, 0, stream>>>(uacc32, iacc32, out);
        return;
    }

    dot_kernel<<<(NQ * EMB + 255) / 256, 256, 0, stream>>>(uacc, iacc, out);
}

// Round 23
// 208.029 us; speedup vs baseline: 1.5818x; 1.0418x over previous
//
#include <hip/hip_runtime.h>

#define NUM_USERS 100000
#define NUM_ITEMS 50000
#define NNZ       2400000
#define EMB       64
#define NTOT      (NUM_USERS + NUM_ITEMS)
#define NQ        16384
#define NBKT      ((NTOT + 255) / 256)        // 586 buckets of 256 rows
#define NAB       ((NNZ + 16383) / 16384)     // append blocks = 147 (16 edges/thread)
#define BCAP      4608                        // bucket capacity (mean 4096 + 8 sigma)
#define BCAP_LO   4096
#define SPILLCAP  32768

typedef unsigned short ushort_t;
typedef unsigned int   uint_t;

// ---------- bf16 helpers (RNE pack, exact unpack) ----------
__device__ __forceinline__ ushort_t f2bf(float f) {
    uint_t u = __float_as_uint(f);
    u += 0x7FFFu + ((u >> 16) & 1u);          // round to nearest even
    return (ushort_t)(u >> 16);
}
__device__ __forceinline__ float bf2f_lo(uint_t w) {   // low 16 bits
    return __uint_as_float(w << 16);
}
__device__ __forceinline__ float bf2f_hi(uint_t w) {   // high 16 bits
    return __uint_as_float(w & 0xFFFF0000u);
}

// ---------- nt helper (scalar element type only) ----------
__device__ __forceinline__ int2 nt_load_i2(const int2* p) {
    unsigned long long u = __builtin_nontemporal_load((const unsigned long long*)p);
    int2 r; r.x = (int)(u & 0xFFFFFFFFull); r.y = (int)(u >> 32);
    return r;
}

// gather-accumulate one edge (8 bf16 dims at octant t)
#define GACC(cc, vv) { \
    uint4 g_ = ((const uint4*)(cur + (size_t)(cc) * EMB))[t]; \
    float v_ = (vv); \
    a0 += v_ * bf2f_lo(g_.x); a1 += v_ * bf2f_hi(g_.x); \
    a2 += v_ * bf2f_lo(g_.y); a3 += v_ * bf2f_hi(g_.y); \
    a4 += v_ * bf2f_lo(g_.z); a5 += v_ * bf2f_hi(g_.z); \
    a6 += v_ * bf2f_lo(g_.w); a7 += v_ * bf2f_hi(g_.w); }

// ---------- fused prologue: cvt + layer-0 query init + counter/qhead init ----------
__global__ void prologue_kernel(const float* __restrict__ eu,
                                const float* __restrict__ ei,
                                const int* __restrict__ users,
                                const int* __restrict__ items,
                                ushort_t* __restrict__ cur,
                                float* __restrict__ uacc,
                                float* __restrict__ iacc,
                                int* __restrict__ ctr,
                                int* __restrict__ cnts,
                                int* __restrict__ qhead) {
    int idx = blockIdx.x * blockDim.x + threadIdx.x;
    const int total4 = NTOT * EMB / 4;                 // 2.4M
    const int user4  = NUM_USERS * EMB / 4;
    if (idx < total4) {                                 // fp32 -> bf16 concat
        float4 v = (idx < user4) ? ((const float4*)eu)[idx]
                                 : ((const float4*)ei)[idx - user4];
        uint2 o;
        o.x = (uint_t)f2bf(v.x) | ((uint_t)f2bf(v.y) << 16);
        o.y = (uint_t)f2bf(v.z) | ((uint_t)f2bf(v.w) << 16);
        ((uint2*)cur)[idx] = o;
    }
    if (idx < NQ * 16) {                                // layer-0 query gather (fp32)
        int j = idx >> 4;
        int t = idx & 15;
        ((float4*)uacc)[idx] = ((const float4*)eu)[(size_t)users[j] * 16 + t];
        ((float4*)iacc)[idx] = ((const float4*)ei)[(size_t)items[j] * 16 + t];
    }
    if (idx < NTOT) qhead[idx] = -1;
    if (idx < NBKT) ctr[idx] = 0;
    if (idx < 8)    cnts[idx] = 0;
}

__global__ void dot_kernel(const float* __restrict__ uacc,
                           const float* __restrict__ iacc,
                           float* __restrict__ out) {
    int idx = blockIdx.x * blockDim.x + threadIdx.x;
    int j = idx >> 6;
    if (j >= NQ) return;
    int d = idx & 63;
    float p = uacc[(size_t)j * EMB + d] * iacc[(size_t)j * EMB + d];
    #pragma unroll
    for (int o = 32; o > 0; o >>= 1) p += __shfl_down(p, o);
    if (d == 0) out[j] = p * (1.0f / 16.0f);
}

// ---------- build: LDS-aggregated fixed-capacity bucket append ----------
// 16 consecutive edges/thread (12x16B loads). 256-row buckets: ~28 records per
// (block,bucket) -> ~86K global grants total, ~99% store-line fill.
// qbuild (inverted query index + compact row list) fused into the first 32K
// global threads (qhead initialized by prologue, consumed only by spmm later).

__global__ __launch_bounds__(1024) void append_agg_kernel(
        const int* __restrict__ row,
        const int* __restrict__ col,
        const float* __restrict__ val,
        const int* __restrict__ users,
        const int* __restrict__ items,
        int* __restrict__ qhead,
        int* __restrict__ qnext,
        int* __restrict__ qrows,
        int* __restrict__ qcnt,
        int* __restrict__ ctr,
        int2* __restrict__ staging,
        int4* __restrict__ spill,
        int* __restrict__ spillcnt,
        int bcap) {
    __shared__ int cnt[NBKT];
    __shared__ int base[NBKT];
    int tid = threadIdx.x;
    int gtid = blockIdx.x * 1024 + tid;
    if (tid < NBKT) cnt[tid] = 0;

    // fused qbuild (blocks 0..31 carry the 32768 query slots)
    if (gtid < 2 * NQ) {
        int r = (gtid < NQ) ? users[gtid] : (NUM_USERS + items[gtid - NQ]);
        int old = atomicExch(&qhead[r], gtid);
        qnext[gtid] = old;
        if (old < 0) {
            int p = atomicAdd(qcnt, 1);
            qrows[p] = r;
        }
    }
    __syncthreads();

    int  myb[16], myr[16];
    int2 rec[16];
    int e0 = gtid * 16;
    bool any = (e0 < NNZ);                       // NNZ % 16 == 0 -> all-or-none
    if (any) {
        #pragma unroll
        for (int h = 0; h < 4; ++h) {
            int4   r4 = *(const int4*)&row[e0 + 4 * h];
            int4   c4 = *(const int4*)&col[e0 + 4 * h];
            float4 v4 = *(const float4*)&val[e0 + 4 * h];
            int   rs_[4] = {r4.x, r4.y, r4.z, r4.w};
            int   cs_[4] = {c4.x, c4.y, c4.z, c4.w};
            float vs_[4] = {v4.x, v4.y, v4.z, v4.w};
            #pragma unroll
            for (int j = 0; j < 4; ++j) {
                int jj = 4 * h + j;
                int r = rs_[j];
                int b = ((unsigned)r) >> 8;
                myb[jj] = b;
                rec[jj] = make_int2(((r & 255) << 18) | cs_[j], __float_as_int(vs_[j]));
                myr[jj] = atomicAdd(&cnt[b], 1);  // local rank
            }
        }
    }
    __syncthreads();
    if (tid < NBKT) {
        int c = cnt[tid];
        base[tid] = c ? atomicAdd(&ctr[tid], c) : 0;
    }
    __syncthreads();
    if (any) {
        #pragma unroll
        for (int j = 0; j < 16; ++j) {
            int p = base[myb[j]] + myr[j];
            if (p < bcap) {
                staging[(size_t)myb[j] * bcap + p] = rec[j];
            } else {
                int sp = atomicAdd(spillcnt, 1);
                if (sp < SPILLCAP) {
                    int r = myb[j] * 256 + (((unsigned)rec[j].x) >> 18);
                    int c = rec[j].x & 0x3FFFF;
                    spill[sp] = make_int4(r, c, rec[j].y, 0);
                }
            }
        }
    }
}

// ---------- within-bucket sort -> CSR (in place, fixed segments) ----------

__global__ __launch_bounds__(512) void csr_fixed_kernel(
        const int* __restrict__ ctr,
        int2* __restrict__ staging,
        int* __restrict__ rs,                    // NBKT * 257
        int bcap) {
    __shared__ int2 recs[BCAP];
    __shared__ int cnt[256];
    __shared__ int sc[256];
    __shared__ int pos[256];
    int tid = threadIdx.x;
    int b = blockIdx.x;
    int base0 = b * bcap;
    int n = min(ctr[b], bcap);

    if (tid < 256) cnt[tid] = 0;
    __syncthreads();
    for (int k = tid; k < n; k += 512) {
        int2 rec = nt_load_i2(&staging[base0 + k]);
        recs[k] = rec;
        atomicAdd(&cnt[((unsigned)rec.x) >> 18], 1);
    }
    __syncthreads();
    if (tid < 256) sc[tid] = cnt[tid];
    __syncthreads();
    #pragma unroll
    for (int o = 1; o < 256; o <<= 1) {          // Hillis-Steele inclusive scan
        int v = 0;
        if (tid < 256 && tid >= o) v = sc[tid - o];
        __syncthreads();
        if (tid < 256) sc[tid] += v;
        __syncthreads();
    }
    if (tid < 256) {
        int p = sc[tid] - cnt[tid];              // exclusive
        pos[tid] = p;
        rs[b * 257 + tid] = base0 + p;           // unconditional (phantoms: p == n)
    }
    if (tid == 0) rs[b * 257 + 256] = base0 + n;
    __syncthreads();
    for (int k = tid; k < n; k += 512) {
        int2 rec = recs[k];
        int rl = ((unsigned)rec.x) >> 18;
        int p = atomicAdd(&pos[rl], 1);
        staging[base0 + p] = make_int2(rec.x & 0x3FFFF, rec.y);
    }
}

// ---------- SpMM (two-path): one wave per row; lane = (edge-slot q 0..7, t 0..7) ----

__global__ __launch_bounds__(256) void spmm_csr_kernel(
        const int* __restrict__ rs,
        const int2* __restrict__ pairs,
        const ushort_t* __restrict__ cur,        // bf16 [NTOT][EMB]
        ushort_t* __restrict__ next,             // bf16 [NTOT][EMB]
        const int* __restrict__ qhead,
        const int* __restrict__ qnext,
        float* __restrict__ uacc) {              // fp32, uacc|iacc contiguous
    int gid = blockIdx.x * blockDim.x + threadIdx.x;
    int r = gid >> 6;          // wave id = row
    if (r >= NTOT) return;
    int lane = threadIdx.x & 63;
    int q = lane >> 3;         // edge slot 0..7
    int t = lane & 7;          // dim octant 0..7 (dims 8t..8t+7)
    int b = r >> 8, i = r & 255;
    int s = rs[b * 257 + i];
    int e = rs[b * 257 + i + 1];
    float a0 = 0.f, a1 = 0.f, a2 = 0.f, a3 = 0.f;
    float a4 = 0.f, a5 = 0.f, a6 = 0.f, a7 = 0.f;
    if (e - s <= 16) {
        // ---- light path: one straight-line 16-edge round ----
        int idx0 = s + q,     ok0 = idx0 < e;
        int idx1 = s + q + 8, ok1 = idx1 < e;
        int2 cv0 = nt_load_i2(&pairs[ok0 ? idx0 : s]);
        int2 cv1 = nt_load_i2(&pairs[ok1 ? idx1 : s]);
        float v0 = ok0 ? __int_as_float(cv0.y) : 0.f;
        float v1 = ok1 ? __int_as_float(cv1.y) : 0.f;
        GACC(cv0.x, v0);
        GACC(cv1.x, v1);
    } else {
        // ---- heavy path: 32-edge rounds, 4 gathers in flight ----
        for (int base = s; base < e; base += 32) {
            int   c[4];
            float v[4];
            #pragma unroll
            for (int k = 0; k < 4; ++k) {
                int idx = base + q + 8 * k;
                bool ok = idx < e;
                int2 cv = nt_load_i2(&pairs[ok ? idx : s]);
                c[k] = cv.x;
                v[k] = ok ? __int_as_float(cv.y) : 0.f;
            }
            #pragma unroll
            for (int k = 0; k < 4; ++k) GACC(c[k], v[k]);
        }
    }
    #pragma unroll
    for (int o = 8; o < 64; o <<= 1) {
        a0 += __shfl_xor(a0, o); a1 += __shfl_xor(a1, o);
        a2 += __shfl_xor(a2, o); a3 += __shfl_xor(a3, o);
        a4 += __shfl_xor(a4, o); a5 += __shfl_xor(a5, o);
        a6 += __shfl_xor(a6, o); a7 += __shfl_xor(a7, o);
    }
    if (q == 0) {
        uint4 o;
        o.x = (uint_t)f2bf(a0) | ((uint_t)f2bf(a1) << 16);
        o.y = (uint_t)f2bf(a2) | ((uint_t)f2bf(a3) << 16);
        o.z = (uint_t)f2bf(a4) | ((uint_t)f2bf(a5) << 16);
        o.w = (uint_t)f2bf(a6) | ((uint_t)f2bf(a7) << 16);
        ((uint4*)(next + (size_t)r * EMB))[t] = o;
        // fused per-layer query accumulate (fp32): lane t covers dims 8t..8t+7
        int si = qhead[r];                       // wave-uniform
        while (si >= 0) {
            float4* dst = (float4*)&uacc[(size_t)si * EMB];
            float4 d0 = dst[2 * t], d1 = dst[2 * t + 1];
            d0.x += a0; d0.y += a1; d0.z += a2; d0.w += a3;
            d1.x += a4; d1.y += a5; d1.z += a6; d1.w += a7;
            dst[2 * t] = d0; dst[2 * t + 1] = d1;
            si = qnext[si];
        }
    }
}

// ---------- last layer: only query rows (no next store, uacc accumulate only) ----

__global__ __launch_bounds__(256) void spmm_last_kernel(
        const int* __restrict__ rs,
        const int2* __restrict__ pairs,
        const ushort_t* __restrict__ cur,
        const int* __restrict__ qhead,
        const int* __restrict__ qnext,
        const int* __restrict__ qrows,
        const int* __restrict__ qcnt,
        float* __restrict__ uacc) {
    int wave = (blockIdx.x * blockDim.x + threadIdx.x) >> 6;
    if (wave >= *qcnt) return;
    int r = qrows[wave];
    int lane = threadIdx.x & 63;
    int q = lane >> 3;
    int t = lane & 7;
    int b = r >> 8, i = r & 255;
    int s = rs[b * 257 + i];
    int e = rs[b * 257 + i + 1];
    float a0 = 0.f, a1 = 0.f, a2 = 0.f, a3 = 0.f;
    float a4 = 0.f, a5 = 0.f, a6 = 0.f, a7 = 0.f;
    if (e - s <= 16) {
        int idx0 = s + q,     ok0 = idx0 < e;
        int idx1 = s + q + 8, ok1 = idx1 < e;
        int2 cv0 = nt_load_i2(&pairs[ok0 ? idx0 : s]);
        int2 cv1 = nt_load_i2(&pairs[ok1 ? idx1 : s]);
        float v0 = ok0 ? __int_as_float(cv0.y) : 0.f;
        float v1 = ok1 ? __int_as_float(cv1.y) : 0.f;
        GACC(cv0.x, v0);
        GACC(cv1.x, v1);
    } else {
        for (int base = s; base < e; base += 32) {
            int   c[4];
            float v[4];
            #pragma unroll
            for (int k = 0; k < 4; ++k) {
                int idx = base + q + 8 * k;
                bool ok = idx < e;
                int2 cv = nt_load_i2(&pairs[ok ? idx : s]);
                c[k] = cv.x;
                v[k] = ok ? __int_as_float(cv.y) : 0.f;
            }
            #pragma unroll
            for (int k = 0; k < 4; ++k) GACC(c[k], v[k]);
        }
    }
    #pragma unroll
    for (int o = 8; o < 64; o <<= 1) {
        a0 += __shfl_xor(a0, o); a1 += __shfl_xor(a1, o);
        a2 += __shfl_xor(a2, o); a3 += __shfl_xor(a3, o);
        a4 += __shfl_xor(a4, o); a5 += __shfl_xor(a5, o);
        a6 += __shfl_xor(a6, o); a7 += __shfl_xor(a7, o);
    }
    if (q == 0) {
        int si = qhead[r];
        while (si >= 0) {
            float4* dst = (float4*)&uacc[(size_t)si * EMB];
            float4 d0 = dst[2 * t], d1 = dst[2 * t + 1];
            d0.x += a0; d0.y += a1; d0.z += a2; d0.w += a3;
            d1.x += a4; d1.y += a5; d1.z += a6; d1.w += a7;
            dst[2 * t] = d0; dst[2 * t + 1] = d1;
            si = qnext[si];
        }
    }
}

// spill edges (statically ~unreachable): CAS on bf16 pair of next
__global__ void spill_apply_kernel(const int4* __restrict__ spill,
                                   const int* __restrict__ spillcnt,
                                   const ushort_t* __restrict__ cur,
                                   ushort_t* __restrict__ next) {
    int n = min(*spillcnt, SPILLCAP);
    for (int idx = blockIdx.x * blockDim.x + threadIdx.x;
         idx < n * 32; idx += gridDim.x * blockDim.x) {
        int e = idx >> 5, w = idx & 31;          // word w covers dims 2w, 2w+1
        int4 rec = spill[e];
        float v = __int_as_float(rec.z);
        float g0 = bf2f_lo((uint_t)cur[(size_t)rec.y * EMB + 2 * w]);
        float g1 = bf2f_lo((uint_t)cur[(size_t)rec.y * EMB + 2 * w + 1]);
        uint_t* addr = (uint_t*)(next + (size_t)rec.x * EMB + 2 * w);
        uint_t old = *addr, assumed;
        do {
            assumed = old;
            float o0 = bf2f_lo(assumed);
            float o1 = bf2f_hi(assumed);
            uint_t nw = (uint_t)f2bf(o0 + v * g0) | ((uint_t)f2bf(o1 + v * g1) << 16);
            old = atomicCAS(addr, assumed, nw);
        } while (old != assumed);
    }
}

// last-layer spill (statically ~unreachable): add into uacc via query chain
__global__ void spill_apply_last_kernel(const int4* __restrict__ spill,
                                        const int* __restrict__ spillcnt,
                                        const ushort_t* __restrict__ cur,
                                        const int* __restrict__ qhead,
                                        const int* __restrict__ qnext,
                                        float* __restrict__ uacc) {
    int n = min(*spillcnt, SPILLCAP);
    for (int idx = blockIdx.x * blockDim.x + threadIdx.x;
         idx < n * EMB; idx += gridDim.x * blockDim.x) {
        int e = idx >> 6, d = idx & 63;
        int4 rec = spill[e];
        float v = __int_as_float(rec.z);
        float g = bf2f_lo((uint_t)cur[(size_t)rec.y * EMB + d]);
        int si = qhead[rec.x];
        while (si >= 0) {
            atomicAdd(&uacc[(size_t)si * EMB + d], v * g);
            si = qnext[si];
        }
    }
}

// ---------- fallback path (ws too small): fp32 atomic SpMM ----------

__global__ void init_cur_kernel(const float* __restrict__ eu,
                                const float* __restrict__ ei,
                                float* __restrict__ cur) {
    int idx = blockIdx.x * blockDim.x + threadIdx.x;
    const int total4 = NTOT * EMB / 4;
    const int user4  = NUM_USERS * EMB / 4;
    if (idx < total4) {
        float4 v;
        if (idx < user4) v = ((const float4*)eu)[idx];
        else             v = ((const float4*)ei)[idx - user4];
        ((float4*)cur)[idx] = v;
    }
}

__global__ void gather_init32_kernel(const int* __restrict__ users,
                                     const int* __restrict__ items,
                                     const float* __restrict__ eu,
                                     const float* __restrict__ ei,
                                     float* __restrict__ uacc,
                                     float* __restrict__ iacc) {
    int idx = blockIdx.x * blockDim.x + threadIdx.x;
    if (idx >= NQ * 16) return;
    int j = idx >> 4;
    int t = idx & 15;
    ((float4*)uacc)[idx] = ((const float4*)eu)[(size_t)users[j] * 16 + t];
    ((float4*)iacc)[idx] = ((const float4*)ei)[(size_t)items[j] * 16 + t];
}

__global__ void gather_add_kernel(const int* __restrict__ users,
                                  const int* __restrict__ items,
                                  const float* __restrict__ src,
                                  float* __restrict__ uacc,
                                  float* __restrict__ iacc) {
    int idx = blockIdx.x * blockDim.x + threadIdx.x;
    if (idx >= NQ * 16) return;
    int j = idx >> 4;
    int t = idx & 15;
    float4 uv = ((const float4*)src)[(size_t)users[j] * 16 + t];
    float4 iv = ((const float4*)src)[(size_t)(NUM_USERS + items[j]) * 16 + t];
    float4* up = (float4*)uacc + idx;
    float4* ip = (float4*)iacc + idx;
    float4 a = *up, b = *ip;
    a.x += uv.x; a.y += uv.y; a.z += uv.z; a.w += uv.w;
    b.x += iv.x; b.y += iv.y; b.z += iv.z; b.w += iv.w;
    *up = a; *ip = b;
}

__global__ void spmm_atomic_kernel(const int* __restrict__ row,
                                   const int* __restrict__ col,
                                   const float* __restrict__ val,
                                   const float* __restrict__ cur,
                                   float* __restrict__ next) {
    long long idx = (long long)blockIdx.x * blockDim.x + threadIdx.x;
    if (idx >= (long long)NNZ * EMB) return;
    int e = (int)(idx >> 6);
    int d = (int)(idx & 63);
    atomicAdd(&next[row[e] * EMB + d], val[e] * cur[col[e] * EMB + d]);
}

extern "C" void kernel_launch(void* const* d_in, const int* in_sizes, int n_in,
                              void* d_out, int out_size, void* d_ws, size_t ws_size,
                              hipStream_t stream) {
    const int*   row   = (const int*)d_in[0];
    const int*   col   = (const int*)d_in[1];
    const float* val   = (const float*)d_in[2];
    const float* eu    = (const float*)d_in[3];
    const float* ei    = (const float*)d_in[4];
    const int*   users = (const int*)d_in[5];
    const int*   items = (const int*)d_in[6];
    float*       out   = (float*)d_out;

    // primary workspace layout (bf16 layer buffers)
    ushort_t* bufA = (ushort_t*)d_ws;                    // NTOT*EMB bf16
    ushort_t* bufB = bufA + (size_t)NTOT * EMB;          // NTOT*EMB bf16
    float* uacc = (float*)(bufB + (size_t)NTOT * EMB);   // NQ*EMB f32
    float* iacc = uacc + (size_t)NQ * EMB;               // NQ*EMB f32 (contiguous!)
    int*   ctr  = (int*)(iacc + (size_t)NQ * EMB);       // NBKT
    int*   rs   = ctr + NBKT;                            // NBKT*257
    int*   spillcnt = rs + NBKT * 257;                   // 4
    int*   qcnt = spillcnt + 4;                          // 4
    int*   qhead = qcnt + 4;                             // NTOT
    int*   qnext = qhead + NTOT;                         // 2*NQ
    int*   qrows = qnext + 2 * NQ;                       // 2*NQ
    int4*  spill = (int4*)(qrows + 2 * NQ);              // SPILLCAP
    int2*  staging = (int2*)(spill + SPILLCAP);          // NBKT*bcap

    size_t fixed_bytes = (size_t)((char*)staging - (char*)d_ws);
    size_t needHi = fixed_bytes + (size_t)NBKT * BCAP * sizeof(int2);
    size_t needLo = fixed_bytes + (size_t)NBKT * BCAP_LO * sizeof(int2);
    int bcap = (ws_size >= needHi) ? BCAP : ((ws_size >= needLo) ? BCAP_LO : 0);

    if (bcap > 0) {
        prologue_kernel<<<(NTOT * 16 + 255) / 256, 256, 0, stream>>>(
            eu, ei, users, items, bufA, uacc, iacc, ctr, spillcnt, qhead);
        append_agg_kernel<<<NAB, 1024, 0, stream>>>(
            row, col, val, users, items, qhead, qnext, qrows, qcnt,
            ctr, staging, spill, spillcnt, bcap);
        csr_fixed_kernel<<<NBKT, 512, 0, stream>>>(ctr, staging, rs, bcap);

        ushort_t* cur = bufA;
        ushort_t* nxt = bufB;
        for (int l = 0; l < 2; ++l) {
            spmm_csr_kernel<<<(NTOT * 64 + 255) / 256, 256, 0, stream>>>(
                rs, staging, cur, nxt, qhead, qnext, uacc);
            spill_apply_kernel<<<4, 256, 0, stream>>>(spill, spillcnt, cur, nxt);
            ushort_t* tmp = cur; cur = nxt; nxt = tmp;
        }
        // last layer: only rows consumed by query chains; no next store
        spmm_last_kernel<<<(2 * NQ * 64 + 255) / 256, 256, 0, stream>>>(
            rs, staging, cur, qhead, qnext, qrows, qcnt, uacc);
        spill_apply_last_kernel<<<4, 256, 0, stream>>>(spill, spillcnt, cur,
                                                       qhead, qnext, uacc);
    } else {
        // fallback (fp32): own layout — bufA32, bufB32, uacc, iacc
        float* bufA32 = (float*)d_ws;
        float* bufB32 = bufA32 + (size_t)NTOT * EMB;
        float* uacc32 = bufB32 + (size_t)NTOT * EMB;
        float* iacc32 = uacc32 + (size_t)NQ * EMB;
        gather_init32_kernel<<<(NQ * 16 + 255) / 256, 256, 0, stream>>>(users, items, eu, ei, uacc32, iacc32);
        init_cur_kernel<<<(NTOT * EMB / 4 + 255) / 256, 256, 0, stream>>>(eu, ei, bufA32);
        float* cur = bufA32;
        float* nxt = bufB32;
        const long long spmm_threads = (long long)NNZ * EMB;
        for (int l = 0; l < 3; ++l) {
            (void)hipMemsetAsync(nxt, 0, (size_t)NTOT * EMB * sizeof(float), stream);
            spmm_atomic_kernel<<<(int)((spmm_threads + 255) / 256), 256, 0, stream>>>(row, col, val, cur, nxt);
            gather_add_kernel<<<(NQ * 16 + 255) / 256, 256, 0, stream>>>(users, items, nxt, uacc32, iacc32);
            float* t = cur; cur = nxt; nxt = t;
        }
        dot_kernel<<<(NQ * EMB + 255) / 256, 256, 0, stream>>>(uacc32, iacc32, out);
        return;
    }

    dot_kernel<<<(NQ * EMB + 255) / 256, 256, 0, stream>>>(uacc, iacc, out);
}